// Round 3
// baseline (68023.987 us; speedup 1.0000x reference)
//
#include <hip/hip_runtime.h>
#include <cstddef>
#include <cstdint>

#define DIM 128
#define NROUNDS 120
#define NNZ_CAP (1 << 20)

typedef _Float16 half8 __attribute__((ext_vector_type(8)));
typedef float f32x16 __attribute__((ext_vector_type(16)));

__device__ __forceinline__ float sigf(float x) { return 1.f / (1.f + __expf(-x)); }
__device__ __forceinline__ float tanh_fast(float x) { return 2.f / (1.f + __expf(-2.f * x)) - 1.f; }

// ---------------- sparse build ----------------
__global__ void count_nz_kernel(const float* __restrict__ adj, int* __restrict__ row_cnt,
                                int* __restrict__ col_cnt, int ncols) {
  int i = blockIdx.x;
  int j = blockIdx.y * blockDim.x + threadIdx.x;
  bool nz = (j < ncols) && (adj[(size_t)i * ncols + j] != 0.f);
  unsigned long long m = __ballot(nz);
  if ((threadIdx.x & 63) == 0) {
    int c = __popcll(m);
    if (c) atomicAdd(&row_cnt[i], c);
  }
  if (nz) atomicAdd(&col_cnt[j], 1);
}

__global__ void scan_kernel(const int* __restrict__ cnt, int* __restrict__ ptr, int n) {
  __shared__ int sdata[256];
  int t = threadIdx.x;
  int per = (n + 255) / 256;
  int beg = t * per;
  int end = beg + per; if (end > n) end = n;
  int local = 0;
  for (int i = beg; i < end; ++i) local += cnt[i];
  sdata[t] = local;
  __syncthreads();
  for (int off = 1; off < 256; off <<= 1) {
    int v = (t >= off) ? sdata[t - off] : 0;
    __syncthreads();
    sdata[t] += v;
    __syncthreads();
  }
  int run = sdata[t] - local;
  for (int i = beg; i < end; ++i) { ptr[i] = run; run += cnt[i]; }
  if (t == 255) ptr[n] = sdata[255];
}

__global__ void fill_nz_kernel(const float* __restrict__ adj, const int* __restrict__ row_ptr,
                               const int* __restrict__ col_ptr, int* __restrict__ row_fill,
                               int* __restrict__ col_fill, int* __restrict__ col_idx,
                               int* __restrict__ row_idx, int ncols) {
  int i = blockIdx.x;
  int j = blockIdx.y * blockDim.x + threadIdx.x;
  if (j >= ncols) return;
  if (adj[(size_t)i * ncols + j] != 0.f) {
    int r = atomicAdd(&row_fill[i], 1);
    col_idx[row_ptr[i] + r] = j;
    int c = atomicAdd(&col_fill[j], 1);
    row_idx[col_ptr[j] + c] = i;
  }
}

// ---------------- weight packing into MFMA B-fragment order (split f16) ----------------
__global__ void pack_w_kernel(const float* __restrict__ src, int out_dim,
                              _Float16* __restrict__ dh, _Float16* __restrict__ dl) {
  int idx = blockIdx.x * 256 + threadIdx.x;
  if (idx >= out_dim * DIM) return;
  int n = idx >> 7, k = idx & 127;
  float x = src[idx];
  _Float16 hi = (_Float16)x;
  _Float16 lo = (_Float16)(x - (float)hi);
  int nt = n >> 5, ks = k >> 4;
  int L = ((k >> 3) & 1) * 32 + (n & 31);
  int j = k & 7;
  int dst = ((nt * 8 + ks) * 64 + L) * 8 + j;
  dh[dst] = hi; dl[dst] = lo;
}

// ---------------- init ----------------
__global__ void init_hc_kernel(const int* __restrict__ values, const float* __restrict__ tW,
                               const float* __restrict__ tb, const float* __restrict__ fW,
                               const float* __restrict__ fb, float* __restrict__ h,
                               float* __restrict__ c, int N) {
  int idx = blockIdx.x * blockDim.x + threadIdx.x;
  if (idx >= N * DIM) return;
  int row = idx >> 7, col = idx & (DIM - 1);
  float tv = tW[col] + tb[col];
  float fv = fW[col] + fb[col];
  h[idx] = (values[row] == 1) ? tv : fv;
  c[idx] = 0.f;
}

// ---------------- LDS swizzle ----------------
__device__ __forceinline__ int sw_idx(int m, int k) {
  return (m << 7) + (((((k >> 3) ^ (m & 15))) << 3) | (k & 7));
}

__device__ __forceinline__ void stage_rows(const float* __restrict__ src, int M, int rb,
                                           _Float16* Sh, _Float16* Sl, int tid) {
  for (int t = tid; t < 32 * 32; t += 256) {
    int r = t >> 5, q = t & 31;
    int row = rb + r;
    float4 v;
    if (row < M) v = *(const float4*)(src + (size_t)row * DIM + q * 4);
    else { v.x = v.y = v.z = v.w = 0.f; }
    int a = sw_idx(r, q * 4);
    float vv[4] = {v.x, v.y, v.z, v.w};
#pragma unroll
    for (int e = 0; e < 4; ++e) {
      _Float16 hi = (_Float16)vv[e];
      Sh[a + e] = hi;
      Sl[a + e] = (_Float16)(vv[e] - (float)hi);
    }
  }
}

// one 32x32 output tile over K=128, split-f16, dual accumulator chains
__device__ __forceinline__ f32x16 gemm_tile(const _Float16* Sh, const _Float16* Sl,
                                            const _Float16* __restrict__ Bh,
                                            const _Float16* __restrict__ Bl,
                                            int nt, int lane, f32x16 acc) {
  int m = lane & 31, hf = lane >> 5;
  f32x16 acc2;
#pragma unroll
  for (int i = 0; i < 16; ++i) acc2[i] = 0.f;
#pragma unroll
  for (int ks = 0; ks < 8; ++ks) {
    int a_off = (m << 7) + ((((ks * 2 + hf) ^ (m & 15))) << 3);
    half8 ah = *(const half8*)(Sh + a_off);
    half8 al = *(const half8*)(Sl + a_off);
    int boff = ((nt * 8 + ks) * 64 + lane) * 8;
    half8 bh = *(const half8*)(Bh + boff);
    half8 bl = *(const half8*)(Bl + boff);
    f32x16& A = (ks & 1) ? acc2 : acc;
    A = __builtin_amdgcn_mfma_f32_32x32x16_f16(ah, bh, A, 0, 0, 0);
    A = __builtin_amdgcn_mfma_f32_32x32x16_f16(ah, bl, A, 0, 0, 0);
    A = __builtin_amdgcn_mfma_f32_32x32x16_f16(al, bh, A, 0, 0, 0);
  }
#pragma unroll
  for (int i = 0; i < 16; ++i) acc[i] += acc2[i];
  return acc;
}

__device__ __forceinline__ void write_cd_lds(f32x16 acc, _Float16* Dh, _Float16* Dl,
                                             int nt, int lane, bool relu) {
  int col = (nt << 5) + (lane & 31);
  int rbase = (lane >> 5) << 2;
#pragma unroll
  for (int reg = 0; reg < 16; ++reg) {
    int row = (reg & 3) + ((reg >> 2) << 3) + rbase;
    float x = acc[reg];
    if (relu) x = fmaxf(x, 0.f);
    _Float16 hi = (_Float16)x;
    int a = sw_idx(row, col);
    Dh[a] = hi;
    Dl[a] = (_Float16)(x - (float)hi);
  }
}

// ---------------- MLP tile (device fn) ----------------
__device__ __forceinline__ void mlp_tile(
    const float* __restrict__ X, int M, int rb,
    const _Float16* __restrict__ W1h, const _Float16* __restrict__ W1l, const float* __restrict__ b1,
    const _Float16* __restrict__ W2h, const _Float16* __restrict__ W2l, const float* __restrict__ b2,
    const _Float16* __restrict__ W3h, const _Float16* __restrict__ W3l, const float* __restrict__ b3,
    float* __restrict__ out,
    _Float16* S0, _Float16* S1, _Float16* S2, _Float16* S3) {
  int tid = threadIdx.x;
  __syncthreads();
  stage_rows(X, M, rb, S0, S1, tid);
  __syncthreads();
  int lane = tid & 63, w = tid >> 6;
  int colw = (w << 5) + (lane & 31);
  f32x16 acc;
  float bv;

  bv = b1[colw];
#pragma unroll
  for (int i = 0; i < 16; ++i) acc[i] = bv;
  acc = gemm_tile(S0, S1, W1h, W1l, w, lane, acc);
  write_cd_lds(acc, S2, S3, w, lane, true);
  __syncthreads();

  bv = b2[colw];
#pragma unroll
  for (int i = 0; i < 16; ++i) acc[i] = bv;
  acc = gemm_tile(S2, S3, W2h, W2l, w, lane, acc);
  write_cd_lds(acc, S0, S1, w, lane, true);
  __syncthreads();

  bv = b3[colw];
#pragma unroll
  for (int i = 0; i < 16; ++i) acc[i] = bv;
  acc = gemm_tile(S0, S1, W3h, W3l, w, lane, acc);

  int rbase = (lane >> 5) << 2;
#pragma unroll
  for (int reg = 0; reg < 16; ++reg) {
    int row = rb + (reg & 3) + ((reg >> 2) << 3) + rbase;
    if (row < M) out[(size_t)row * DIM + colw] = acc[reg];
  }
}

// ---------------- LSTM tile (gather + 2 gemms + elementwise) ----------------
__device__ __forceinline__ void lstm_tile(
    const int* __restrict__ ptr, const int* __restrict__ nzidx, const float* __restrict__ va,
    float* __restrict__ hbuf, float* __restrict__ cbuf, int M, int rb,
    const _Float16* __restrict__ Wxh, const _Float16* __restrict__ Wxl,
    const _Float16* __restrict__ Whh_, const _Float16* __restrict__ Whl,
    const float* __restrict__ bih, const float* __restrict__ bhh,
    _Float16* Xh, _Float16* Xl, _Float16* Hh, _Float16* Hl) {
  int tid = threadIdx.x;
  __syncthreads();
  stage_rows(hbuf, M, rb, Hh, Hl, tid);
  {
    int r = tid >> 3, seg = tid & 7;
    int row = rb + r;
    float a[16];
#pragma unroll
    for (int e = 0; e < 16; ++e) a[e] = 0.f;
    if (row < M) {
      int s = ptr[row], e_ = ptr[row + 1];
      int p = s;
      for (; p + 4 <= e_; p += 4) {
        int i0 = nzidx[p], i1 = nzidx[p + 1], i2 = nzidx[p + 2], i3 = nzidx[p + 3];
        const float4* q0 = (const float4*)(va + (size_t)i0 * DIM + seg * 16);
        const float4* q1 = (const float4*)(va + (size_t)i1 * DIM + seg * 16);
        const float4* q2 = (const float4*)(va + (size_t)i2 * DIM + seg * 16);
        const float4* q3 = (const float4*)(va + (size_t)i3 * DIM + seg * 16);
        float4 w0[4], w1[4], w2[4], w3[4];
#pragma unroll
        for (int q = 0; q < 4; ++q) { w0[q] = q0[q]; w1[q] = q1[q]; w2[q] = q2[q]; w3[q] = q3[q]; }
#pragma unroll
        for (int q = 0; q < 4; ++q) {
          a[q * 4 + 0] += (w0[q].x + w1[q].x) + (w2[q].x + w3[q].x);
          a[q * 4 + 1] += (w0[q].y + w1[q].y) + (w2[q].y + w3[q].y);
          a[q * 4 + 2] += (w0[q].z + w1[q].z) + (w2[q].z + w3[q].z);
          a[q * 4 + 3] += (w0[q].w + w1[q].w) + (w2[q].w + w3[q].w);
        }
      }
      for (; p < e_; ++p) {
        const float* src = va + (size_t)nzidx[p] * DIM + seg * 16;
#pragma unroll
        for (int q = 0; q < 4; ++q) {
          float4 v = *(const float4*)(src + q * 4);
          a[q * 4 + 0] += v.x; a[q * 4 + 1] += v.y;
          a[q * 4 + 2] += v.z; a[q * 4 + 3] += v.w;
        }
      }
    }
    int k0 = seg * 16;
#pragma unroll
    for (int e = 0; e < 16; ++e) {
      int aidx = sw_idx(r, k0 + e);
      _Float16 hi = (_Float16)a[e];
      Xh[aidx] = hi;
      Xl[aidx] = (_Float16)(a[e] - (float)hi);
    }
  }
  __syncthreads();

  int lane = tid & 63, w = tid >> 6;
  int m = lane & 31, hf = lane >> 5;
  f32x16 acc[4];
#pragma unroll
  for (int g = 0; g < 4; ++g) {
    int col = (g << 7) + (w << 5) + (lane & 31);
    float bv = bih[col] + bhh[col];
#pragma unroll
    for (int i = 0; i < 16; ++i) acc[g][i] = bv;
  }
#pragma unroll
  for (int ks = 0; ks < 8; ++ks) {
    int a_off = (m << 7) + ((((ks * 2 + hf) ^ (m & 15))) << 3);
    half8 ah = *(const half8*)(Xh + a_off);
    half8 al = *(const half8*)(Xl + a_off);
#pragma unroll
    for (int g = 0; g < 4; ++g) {
      int nt = (g << 2) + w;
      int boff = ((nt * 8 + ks) * 64 + lane) * 8;
      half8 bh = *(const half8*)(Wxh + boff);
      half8 bl = *(const half8*)(Wxl + boff);
      acc[g] = __builtin_amdgcn_mfma_f32_32x32x16_f16(ah, bh, acc[g], 0, 0, 0);
      acc[g] = __builtin_amdgcn_mfma_f32_32x32x16_f16(ah, bl, acc[g], 0, 0, 0);
      acc[g] = __builtin_amdgcn_mfma_f32_32x32x16_f16(al, bh, acc[g], 0, 0, 0);
    }
  }
#pragma unroll
  for (int ks = 0; ks < 8; ++ks) {
    int a_off = (m << 7) + ((((ks * 2 + hf) ^ (m & 15))) << 3);
    half8 ah = *(const half8*)(Hh + a_off);
    half8 al = *(const half8*)(Hl + a_off);
#pragma unroll
    for (int g = 0; g < 4; ++g) {
      int nt = (g << 2) + w;
      int boff = ((nt * 8 + ks) * 64 + lane) * 8;
      half8 bh = *(const half8*)(Whh_ + boff);
      half8 bl = *(const half8*)(Whl + boff);
      acc[g] = __builtin_amdgcn_mfma_f32_32x32x16_f16(ah, bh, acc[g], 0, 0, 0);
      acc[g] = __builtin_amdgcn_mfma_f32_32x32x16_f16(ah, bl, acc[g], 0, 0, 0);
      acc[g] = __builtin_amdgcn_mfma_f32_32x32x16_f16(al, bh, acc[g], 0, 0, 0);
    }
  }
  int cw = (w << 5) + (lane & 31);
  int rbase = (lane >> 5) << 2;
#pragma unroll
  for (int reg = 0; reg < 16; ++reg) {
    int row = rb + (reg & 3) + ((reg >> 2) << 3) + rbase;
    if (row < M) {
      float iv = sigf(acc[0][reg]);
      float fv = sigf(acc[1][reg]);
      float gv = tanh_fast(acc[2][reg]);
      float ov = sigf(acc[3][reg]);
      size_t o = (size_t)row * DIM + cw;
      float cn = fv * cbuf[o] + iv * gv;
      cbuf[o] = cn;
      hbuf[o] = ov * tanh_fast(cn);
    }
  }
}

// ---------------- grid barrier (device-scope, monotone generation) ----------------
__device__ __forceinline__ void gbar(int* cnt, int* gen, int* my_gen) {
  __syncthreads();
  if (threadIdx.x == 0) {
    int g = ++(*my_gen);
    __threadfence();  // release: flush our writes to coherence point
    int target = g * (int)gridDim.x;
    if (atomicAdd(cnt, 1) + 1 == target) {
      __hip_atomic_store(gen, g, __ATOMIC_RELEASE, __HIP_MEMORY_SCOPE_AGENT);
    } else {
      while (__hip_atomic_load(gen, __ATOMIC_RELAXED, __HIP_MEMORY_SCOPE_AGENT) < g)
        __builtin_amdgcn_s_sleep(1);
    }
    __threadfence();  // acquire: invalidate stale L1/L2 before reading others' data
  }
  __syncthreads();
}

// ---------------- persistent round-loop kernel ----------------
#define SZ128 (DIM * DIM)
#define SZ512 (4 * DIM * DIM)
#define O_CM1 0
#define O_CM2 (SZ128)
#define O_CM3 (2 * SZ128)
#define O_PM1 (3 * SZ128)
#define O_PM2 (4 * SZ128)
#define O_PM3 (5 * SZ128)
#define O_VUX (6 * SZ128)
#define O_VUH (6 * SZ128 + SZ512)
#define O_NUX (6 * SZ128 + 2 * SZ512)
#define O_NUH (6 * SZ128 + 3 * SZ512)

__global__ __launch_bounds__(256, 2) void persist_kernel(
    float* __restrict__ h, float* __restrict__ cb, float* __restrict__ va,
    const int* __restrict__ row_ptr, const int* __restrict__ col_idx,
    const int* __restrict__ col_ptr, const int* __restrict__ row_idx,
    const _Float16* __restrict__ ph, const _Float16* __restrict__ pl,
    const float* __restrict__ cm_b1, const float* __restrict__ cm_b2, const float* __restrict__ cm_b3,
    const float* __restrict__ pm_b1, const float* __restrict__ pm_b2, const float* __restrict__ pm_b3,
    const float* __restrict__ vu_bih, const float* __restrict__ vu_bhh,
    const float* __restrict__ nu_bih, const float* __restrict__ nu_bhh,
    int N, int n_nodes, int* bar_cnt, int* bar_gen) {
  __shared__ _Float16 S0[4096], S1[4096], S2[4096], S3[4096];
  int my_gen = 0;
  int tiles_N = (N + 31) >> 5;
  int tiles_n = (n_nodes + 31) >> 5;

  for (int r = 0; r < NROUNDS; ++r) {
    // A: var_pre = cm_mlp(h) over all N rows -> va
    for (int t = blockIdx.x; t < tiles_N; t += gridDim.x)
      mlp_tile(h, N, t << 5, ph + O_CM1, pl + O_CM1, cm_b1, ph + O_CM2, pl + O_CM2, cm_b2,
               ph + O_CM3, pl + O_CM3, cm_b3, va, S0, S1, S2, S3);
    gbar(bar_cnt, bar_gen, &my_gen);
    // B: vu LSTM on rows < n_nodes, X = row-CSR gather of va
    for (int t = blockIdx.x; t < tiles_n; t += gridDim.x)
      lstm_tile(row_ptr, col_idx, va, h, cb, n_nodes, t << 5,
                ph + O_VUX, pl + O_VUX, ph + O_VUH, pl + O_VUH, vu_bih, vu_bhh,
                S0, S1, S2, S3);
    gbar(bar_cnt, bar_gen, &my_gen);
    // C: node_pre = pm_mlp(h[:n_nodes]) -> va
    for (int t = blockIdx.x; t < tiles_n; t += gridDim.x)
      mlp_tile(h, n_nodes, t << 5, ph + O_PM1, pl + O_PM1, pm_b1, ph + O_PM2, pl + O_PM2, pm_b2,
               ph + O_PM3, pl + O_PM3, pm_b3, va, S0, S1, S2, S3);
    gbar(bar_cnt, bar_gen, &my_gen);
    // D: nu LSTM on all N rows, X = CSC gather of va
    for (int t = blockIdx.x; t < tiles_N; t += gridDim.x)
      lstm_tile(col_ptr, row_idx, va, h, cb, N, t << 5,
                ph + O_NUX, pl + O_NUX, ph + O_NUH, pl + O_NUH, nu_bih, nu_bhh,
                S0, S1, S2, S3);
    gbar(bar_cnt, bar_gen, &my_gen);
  }
}

// ---------------- final vote MLP (fp32, runs once) ----------------
__device__ __forceinline__ void tile_gemm(const float* S, const float* __restrict__ W,
                                          int colB, int rowB, float acc[4][4]) {
#pragma unroll 4
  for (int kc = 0; kc < DIM; kc += 4) {
    float4 xv[4], wv[4];
#pragma unroll
    for (int r = 0; r < 4; ++r) xv[r] = *(const float4*)(S + (rowB + r) * DIM + kc);
#pragma unroll
    for (int c = 0; c < 4; ++c) wv[c] = *(const float4*)(W + (size_t)(colB + c) * DIM + kc);
#pragma unroll
    for (int r = 0; r < 4; ++r)
#pragma unroll
      for (int c = 0; c < 4; ++c)
        acc[r][c] += xv[r].x * wv[c].x + xv[r].y * wv[c].y + xv[r].z * wv[c].z + xv[r].w * wv[c].w;
  }
}

__device__ __forceinline__ void layer_lds(const float* Sin, float* Sout,
                                          const float* __restrict__ W, const float* __restrict__ B,
                                          bool relu, int colB, int rowB) {
  float acc[4][4];
#pragma unroll
  for (int r = 0; r < 4; ++r)
#pragma unroll
    for (int cc = 0; cc < 4; ++cc) acc[r][cc] = B[colB + cc];
  tile_gemm(Sin, W, colB, rowB, acc);
#pragma unroll
  for (int r = 0; r < 4; ++r) {
    float4 v;
    v.x = acc[r][0]; v.y = acc[r][1]; v.z = acc[r][2]; v.w = acc[r][3];
    if (relu) { v.x = fmaxf(v.x, 0.f); v.y = fmaxf(v.y, 0.f); v.z = fmaxf(v.z, 0.f); v.w = fmaxf(v.w, 0.f); }
    *(float4*)&Sout[(rowB + r) * DIM + colB] = v;
  }
  __syncthreads();
}

__global__ __launch_bounds__(256) void vote_kernel(
    const float* __restrict__ X, int M,
    const float* __restrict__ W1, const float* __restrict__ b1,
    const float* __restrict__ W2, const float* __restrict__ b2,
    const float* __restrict__ W3, const float* __restrict__ b3,
    float* __restrict__ out) {
  __shared__ float Xs[32 * DIM];
  __shared__ float Ys[32 * DIM];
  int tid = threadIdx.x;
  int rb = blockIdx.x * 32;
  int mrows = M - rb; if (mrows > 32) mrows = 32;
  {
    const float4* src = (const float4*)(X + (size_t)rb * DIM);
    float4* dst = (float4*)Xs;
    int nf4 = mrows * (DIM / 4);
    for (int t = tid; t < 32 * (DIM / 4); t += 256) {
      float4 v;
      if (t < nf4) v = src[t];
      else { v.x = v.y = v.z = v.w = 0.f; }
      dst[t] = v;
    }
  }
  __syncthreads();
  int tx = tid & 31, ty = tid >> 5;
  int colB = tx * 4, rowB = ty * 4;
  layer_lds(Xs, Ys, W1, b1, true, colB, rowB);
  layer_lds(Ys, Xs, W2, b2, true, colB, rowB);
  if (tid < 32) {
    int gr = rb + tid;
    if (gr < M) {
      float s = b3[0];
      for (int k = 0; k < DIM; ++k) s += Xs[tid * DIM + k] * W3[k];
      out[gr] = s;
    }
  }
}

extern "C" void kernel_launch(void* const* d_in, const int* in_sizes, int n_in,
                              void* d_out, int out_size, void* d_ws, size_t ws_size,
                              hipStream_t stream) {
  const float* adj    = (const float*)d_in[0];
  const int*   values = (const int*)d_in[1];
  const int N       = in_sizes[1];                  // 9000
  const int n_nodes = in_sizes[0] / N;              // 8000
  const int n_vars  = N - n_nodes;                  // 1000

  const float* true_W  = (const float*)d_in[3];
  const float* true_b  = (const float*)d_in[4];
  const float* false_W = (const float*)d_in[5];
  const float* false_b = (const float*)d_in[6];
  const float* cm_W1 = (const float*)d_in[7];
  const float* cm_b1 = (const float*)d_in[8];
  const float* cm_W2 = (const float*)d_in[9];
  const float* cm_b2 = (const float*)d_in[10];
  const float* cm_W3 = (const float*)d_in[11];
  const float* cm_b3 = (const float*)d_in[12];
  const float* pm_W1 = (const float*)d_in[13];
  const float* pm_b1 = (const float*)d_in[14];
  const float* pm_W2 = (const float*)d_in[15];
  const float* pm_b2 = (const float*)d_in[16];
  const float* pm_W3 = (const float*)d_in[17];
  const float* pm_b3 = (const float*)d_in[18];
  const float* vv_W1 = (const float*)d_in[19];
  const float* vv_b1 = (const float*)d_in[20];
  const float* vv_W2 = (const float*)d_in[21];
  const float* vv_b2 = (const float*)d_in[22];
  const float* vv_W3 = (const float*)d_in[23];
  const float* vv_b3 = (const float*)d_in[24];
  const float* vu_Wih = (const float*)d_in[25];
  const float* vu_Whh = (const float*)d_in[26];
  const float* vu_bih = (const float*)d_in[27];
  const float* vu_bhh = (const float*)d_in[28];
  const float* nu_Wih = (const float*)d_in[29];
  const float* nu_Whh = (const float*)d_in[30];
  const float* nu_bih = (const float*)d_in[31];
  const float* nu_bhh = (const float*)d_in[32];

  uintptr_t p = (uintptr_t)d_ws;
  auto take = [&](size_t bytes) -> void* {
    uintptr_t cur = (p + 255) & ~(uintptr_t)255;
    p = cur + bytes;
    return (void*)cur;
  };
  float* h  = (float*)take((size_t)N * DIM * sizeof(float));
  float* cb = (float*)take((size_t)N * DIM * sizeof(float));
  float* va = (float*)take((size_t)N * DIM * sizeof(float));
  int* row_ptr = (int*)take((size_t)(n_nodes + 1) * sizeof(int));
  int* col_ptr = (int*)take((size_t)(N + 1) * sizeof(int));
  int* cnts    = (int*)take((size_t)2 * (n_nodes + N) * sizeof(int));
  int* row_cnt  = cnts;
  int* col_cnt  = cnts + n_nodes;
  int* row_fill = cnts + n_nodes + N;
  int* col_fill = cnts + 2 * n_nodes + N;
  int* col_idx = (int*)take((size_t)NNZ_CAP * sizeof(int));
  int* row_idx = (int*)take((size_t)NNZ_CAP * sizeof(int));
  int* bar = (int*)take(256);  // bar[0]=cnt, bar[1]=gen

  size_t tot_pack = (size_t)6 * SZ128 + (size_t)4 * SZ512;
  _Float16* packh = (_Float16*)take(tot_pack * sizeof(_Float16));
  _Float16* packl = (_Float16*)take(tot_pack * sizeof(_Float16));

  hipMemsetAsync(cnts, 0, (size_t)2 * (n_nodes + N) * sizeof(int), stream);
  hipMemsetAsync(bar, 0, 256, stream);
  dim3 cgrid(n_nodes, (N + 255) / 256);
  count_nz_kernel<<<cgrid, 256, 0, stream>>>(adj, row_cnt, col_cnt, N);
  scan_kernel<<<1, 256, 0, stream>>>(row_cnt, row_ptr, n_nodes);
  scan_kernel<<<1, 256, 0, stream>>>(col_cnt, col_ptr, N);
  fill_nz_kernel<<<cgrid, 256, 0, stream>>>(adj, row_ptr, col_ptr, row_fill, col_fill,
                                            col_idx, row_idx, N);
  init_hc_kernel<<<(N * DIM + 255) / 256, 256, 0, stream>>>(values, true_W, true_b,
                                                            false_W, false_b, h, cb, N);

  auto pack = [&](const float* src, int out_dim, size_t o) {
    pack_w_kernel<<<(out_dim * DIM + 255) / 256, 256, 0, stream>>>(src, out_dim,
                                                                   packh + o, packl + o);
  };
  pack(cm_W1, DIM, O_CM1); pack(cm_W2, DIM, O_CM2); pack(cm_W3, DIM, O_CM3);
  pack(pm_W1, DIM, O_PM1); pack(pm_W2, DIM, O_PM2); pack(pm_W3, DIM, O_PM3);
  pack(vu_Wih, 4 * DIM, O_VUX); pack(vu_Whh, 4 * DIM, O_VUH);
  pack(nu_Wih, 4 * DIM, O_NUX); pack(nu_Whh, 4 * DIM, O_NUH);

  int nblocks = (N + 31) / 32;  // 282: >= tiles of every phase; all co-resident (2 blocks/CU cap)
  persist_kernel<<<nblocks, 256, 0, stream>>>(
      h, cb, va, row_ptr, col_idx, col_ptr, row_idx, packh, packl,
      cm_b1, cm_b2, cm_b3, pm_b1, pm_b2, pm_b3,
      vu_bih, vu_bhh, nu_bih, nu_bhh, N, n_nodes, bar, bar + 1);

  vote_kernel<<<(n_vars + 31) / 32, 256, 0, stream>>>(h + (size_t)n_nodes * DIM, n_vars,
      vv_W1, vv_b1, vv_W2, vv_b2, vv_W3, vv_b3, (float*)d_out);
}

// Round 5
// 42983.707 us; speedup vs baseline: 1.5826x; 1.5826x over previous
//
#include <hip/hip_runtime.h>
#include <cstddef>
#include <cstdint>

#define DIM 128
#define NROUNDS 120
#define NNZ_CAP (1 << 20)

typedef _Float16 half8 __attribute__((ext_vector_type(8)));
typedef float f32x16 __attribute__((ext_vector_type(16)));
typedef unsigned long long u64;

__device__ __forceinline__ float sigf(float x) { return 1.f / (1.f + __expf(-x)); }
__device__ __forceinline__ float tanh_fast(float x) { return 2.f / (1.f + __expf(-2.f * x)) - 1.f; }

// ---------------- sparse build (deterministic) ----------------
__global__ void count_nz_kernel(const float* __restrict__ adj, int* __restrict__ row_cnt,
                                int* __restrict__ col_cnt, int ncols) {
  int i = blockIdx.x;
  int j = blockIdx.y * blockDim.x + threadIdx.x;
  bool nz = (j < ncols) && (adj[(size_t)i * ncols + j] != 0.f);
  unsigned long long m = __ballot(nz);
  if ((threadIdx.x & 63) == 0) {
    int c = __popcll(m);
    if (c) atomicAdd(&row_cnt[i], c);
  }
  if (nz) atomicAdd(&col_cnt[j], 1);  // value deterministic (order-independent)
}

__global__ void scan_kernel(const int* __restrict__ cnt, int* __restrict__ ptr, int n) {
  __shared__ int sdata[256];
  int t = threadIdx.x;
  int per = (n + 255) / 256;
  int beg = t * per;
  int end = beg + per; if (end > n) end = n;
  int local = 0;
  for (int i = beg; i < end; ++i) local += cnt[i];
  sdata[t] = local;
  __syncthreads();
  for (int off = 1; off < 256; off <<= 1) {
    int v = (t >= off) ? sdata[t - off] : 0;
    __syncthreads();
    sdata[t] += v;
    __syncthreads();
  }
  int run = sdata[t] - local;
  for (int i = beg; i < end; ++i) { ptr[i] = run; run += cnt[i]; }
  if (t == 255) ptr[n] = sdata[255];
}

// deterministic CSR fill: one wave per row, ballot-prefix placement (ascending cols)
__global__ __launch_bounds__(64) void fill_csr_kernel(const float* __restrict__ adj,
                                                      const int* __restrict__ row_ptr,
                                                      int* __restrict__ col_idx, int ncols) {
  int row = blockIdx.x;
  int lane = threadIdx.x;
  int base = row_ptr[row];
  int cursor = 0;
  const float* arow = adj + (size_t)row * ncols;
  for (int j0 = 0; j0 < ncols; j0 += 64) {
    int j = j0 + lane;
    bool nz = (j < ncols) && (arow[j] != 0.f);
    u64 m = __ballot(nz);
    int pre = __popcll(m & ((1ull << lane) - 1));
    if (nz) col_idx[base + cursor + pre] = j;
    cursor += __popcll(m);
  }
}

// deterministic CSC fill: thread owns one column, scans rows ascending (coalesced across threads)
__global__ __launch_bounds__(64) void fill_csc_kernel(const float* __restrict__ adj,
                                                      const int* __restrict__ col_ptr,
                                                      int* __restrict__ row_idx,
                                                      int nrows, int ncols) {
  int c = blockIdx.x * 64 + threadIdx.x;
  if (c >= ncols) return;
  int cur = col_ptr[c];
  for (int i = 0; i < nrows; ++i) {
    if (adj[(size_t)i * ncols + c] != 0.f) row_idx[cur++] = i;
  }
}

// ---------------- weight packing into MFMA B-fragment order (split f16) ----------------
__global__ void pack_w_kernel(const float* __restrict__ src, int out_dim,
                              _Float16* __restrict__ dh, _Float16* __restrict__ dl) {
  int idx = blockIdx.x * 256 + threadIdx.x;
  if (idx >= out_dim * DIM) return;
  int n = idx >> 7, k = idx & 127;
  float x = src[idx];
  _Float16 hi = (_Float16)x;
  _Float16 lo = (_Float16)(x - (float)hi);
  int nt = n >> 5, ks = k >> 4;
  int L = ((k >> 3) & 1) * 32 + (n & 31);
  int j = k & 7;
  int dst = ((nt * 8 + ks) * 64 + L) * 8 + j;
  dh[dst] = hi; dl[dst] = lo;
}

// ---------------- init ----------------
__global__ void init_hc_kernel(const int* __restrict__ values, const float* __restrict__ tW,
                               const float* __restrict__ tb, const float* __restrict__ fW,
                               const float* __restrict__ fb, float* __restrict__ h,
                               float* __restrict__ c, int N) {
  int idx = blockIdx.x * blockDim.x + threadIdx.x;
  if (idx >= N * DIM) return;
  int row = idx >> 7, col = idx & (DIM - 1);
  float tv = tW[col] + tb[col];
  float fv = fW[col] + fb[col];
  h[idx] = (values[row] == 1) ? tv : fv;
  c[idx] = 0.f;
}

// ---------------- LDS swizzle ----------------
__device__ __forceinline__ int sw_idx(int m, int k) {
  return (m << 7) + (((((k >> 3) ^ (m & 15))) << 3) | (k & 7));
}

// stage 32 fp32 rows (CACHED loads; h/c are block-affine) -> split f16 LDS
__device__ __forceinline__ void stage_rows(const float* __restrict__ src, int M, int rb,
                                           _Float16* Sh, _Float16* Sl, int tid) {
  for (int t = tid; t < 32 * 32; t += 256) {
    int r = t >> 5, q = t & 31;
    int row = rb + r;
    float4 v;
    if (row < M) v = *(const float4*)(src + (size_t)row * DIM + q * 4);
    else { v.x = v.y = v.z = v.w = 0.f; }
    int a = sw_idx(r, q * 4);
    float vv[4] = {v.x, v.y, v.z, v.w};
#pragma unroll
    for (int e = 0; e < 4; ++e) {
      _Float16 hi = (_Float16)vv[e];
      Sh[a + e] = hi;
      Sl[a + e] = (_Float16)(vv[e] - (float)hi);
    }
  }
}

// coherent (L1/L2-bypass) va store, 4B
__device__ __forceinline__ void st_va(float* p, float v) {
  asm volatile("global_store_dword %0, %1, off sc0 sc1" :: "v"(p), "v"(v) : "memory");
}

// one 32x32 output tile over K=128, split-f16, dual accumulator chains
__device__ __forceinline__ f32x16 gemm_tile(const _Float16* Sh, const _Float16* Sl,
                                            const _Float16* __restrict__ Bh,
                                            const _Float16* __restrict__ Bl,
                                            int nt, int lane, f32x16 acc) {
  int m = lane & 31, hf = lane >> 5;
  f32x16 acc2;
#pragma unroll
  for (int i = 0; i < 16; ++i) acc2[i] = 0.f;
#pragma unroll
  for (int ks = 0; ks < 8; ++ks) {
    int a_off = (m << 7) + ((((ks * 2 + hf) ^ (m & 15))) << 3);
    half8 ah = *(const half8*)(Sh + a_off);
    half8 al = *(const half8*)(Sl + a_off);
    int boff = ((nt * 8 + ks) * 64 + lane) * 8;
    half8 bh = *(const half8*)(Bh + boff);
    half8 bl = *(const half8*)(Bl + boff);
    f32x16& A = (ks & 1) ? acc2 : acc;
    A = __builtin_amdgcn_mfma_f32_32x32x16_f16(ah, bh, A, 0, 0, 0);
    A = __builtin_amdgcn_mfma_f32_32x32x16_f16(ah, bl, A, 0, 0, 0);
    A = __builtin_amdgcn_mfma_f32_32x32x16_f16(al, bh, A, 0, 0, 0);
  }
#pragma unroll
  for (int i = 0; i < 16; ++i) acc[i] += acc2[i];
  return acc;
}

__device__ __forceinline__ void write_cd_lds(f32x16 acc, _Float16* Dh, _Float16* Dl,
                                             int nt, int lane, bool relu) {
  int col = (nt << 5) + (lane & 31);
  int rbase = (lane >> 5) << 2;
#pragma unroll
  for (int reg = 0; reg < 16; ++reg) {
    int row = (reg & 3) + ((reg >> 2) << 3) + rbase;
    float x = acc[reg];
    if (relu) x = fmaxf(x, 0.f);
    _Float16 hi = (_Float16)x;
    int a = sw_idx(row, col);
    Dh[a] = hi;
    Dl[a] = (_Float16)(x - (float)hi);
  }
}

// ---------------- MLP tile: cached h in, coherent va out ----------------
__device__ __forceinline__ void mlp_tile(
    const float* __restrict__ X, int M, int rb,
    const _Float16* __restrict__ W1h, const _Float16* __restrict__ W1l, const float* __restrict__ b1,
    const _Float16* __restrict__ W2h, const _Float16* __restrict__ W2l, const float* __restrict__ b2,
    const _Float16* __restrict__ W3h, const _Float16* __restrict__ W3l, const float* __restrict__ b3,
    float* __restrict__ out,
    _Float16* S0, _Float16* S1, _Float16* S2, _Float16* S3) {
  int tid = threadIdx.x;
  __syncthreads();
  stage_rows(X, M, rb, S0, S1, tid);
  __syncthreads();
  int lane = tid & 63, w = tid >> 6;
  int colw = (w << 5) + (lane & 31);
  f32x16 acc;
  float bv;

  bv = b1[colw];
#pragma unroll
  for (int i = 0; i < 16; ++i) acc[i] = bv;
  acc = gemm_tile(S0, S1, W1h, W1l, w, lane, acc);
  write_cd_lds(acc, S2, S3, w, lane, true);
  __syncthreads();

  bv = b2[colw];
#pragma unroll
  for (int i = 0; i < 16; ++i) acc[i] = bv;
  acc = gemm_tile(S2, S3, W2h, W2l, w, lane, acc);
  write_cd_lds(acc, S0, S1, w, lane, true);
  __syncthreads();

  bv = b3[colw];
#pragma unroll
  for (int i = 0; i < 16; ++i) acc[i] = bv;
  acc = gemm_tile(S0, S1, W3h, W3l, w, lane, acc);

  int rbase = (lane >> 5) << 2;
#pragma unroll
  for (int reg = 0; reg < 16; ++reg) {
    int row = rb + (reg & 3) + ((reg >> 2) << 3) + rbase;
    if (row < M) st_va(out + (size_t)row * DIM + colw, acc[reg]);
  }
}

#define ACC4(rr, off_) { a[off_+0] += rr.x; a[off_+1] += rr.y; a[off_+2] += rr.z; a[off_+3] += rr.w; }

// ---------------- LSTM tile: coherent va gather, cached h/c ----------------
__device__ __forceinline__ void lstm_tile(
    const int* __restrict__ ptr, const int* __restrict__ nzidx, const float* __restrict__ va,
    float* __restrict__ hbuf, float* __restrict__ cbuf, int M, int rb,
    const _Float16* __restrict__ Wxh, const _Float16* __restrict__ Wxl,
    const _Float16* __restrict__ Whh_, const _Float16* __restrict__ Whl,
    const float* __restrict__ bih, const float* __restrict__ bhh,
    _Float16* Xh, _Float16* Xl, _Float16* Hh, _Float16* Hl) {
  int tid = threadIdx.x;
  __syncthreads();
  stage_rows(hbuf, M, rb, Hh, Hl, tid);
  {
    int r = tid >> 3, seg = tid & 7;
    int row = rb + r;
    float a[16];
#pragma unroll
    for (int e = 0; e < 16; ++e) a[e] = 0.f;
    if (row < M) {
      int s = ptr[row], e_ = ptr[row + 1];
      int p = s;
      for (; p + 4 <= e_; p += 4) {
        const float* b0 = va + (size_t)nzidx[p] * DIM + seg * 16;
        const float* b1 = va + (size_t)nzidx[p + 1] * DIM + seg * 16;
        const float* b2 = va + (size_t)nzidx[p + 2] * DIM + seg * 16;
        const float* b3 = va + (size_t)nzidx[p + 3] * DIM + seg * 16;
        float4 r0, r1, r2, r3, r4, r5, r6, r7, r8, r9, rA, rB, rC, rD, rE, rF;
        asm volatile(
            "global_load_dwordx4 %0, %16, off sc0 sc1\n\t"
            "global_load_dwordx4 %1, %16, off offset:16 sc0 sc1\n\t"
            "global_load_dwordx4 %2, %16, off offset:32 sc0 sc1\n\t"
            "global_load_dwordx4 %3, %16, off offset:48 sc0 sc1\n\t"
            "global_load_dwordx4 %4, %17, off sc0 sc1\n\t"
            "global_load_dwordx4 %5, %17, off offset:16 sc0 sc1\n\t"
            "global_load_dwordx4 %6, %17, off offset:32 sc0 sc1\n\t"
            "global_load_dwordx4 %7, %17, off offset:48 sc0 sc1\n\t"
            "global_load_dwordx4 %8, %18, off sc0 sc1\n\t"
            "global_load_dwordx4 %9, %18, off offset:16 sc0 sc1\n\t"
            "global_load_dwordx4 %10, %18, off offset:32 sc0 sc1\n\t"
            "global_load_dwordx4 %11, %18, off offset:48 sc0 sc1\n\t"
            "global_load_dwordx4 %12, %19, off sc0 sc1\n\t"
            "global_load_dwordx4 %13, %19, off offset:16 sc0 sc1\n\t"
            "global_load_dwordx4 %14, %19, off offset:32 sc0 sc1\n\t"
            "global_load_dwordx4 %15, %19, off offset:48 sc0 sc1\n\t"
            "s_waitcnt vmcnt(0)"
            : "=&v"(r0), "=&v"(r1), "=&v"(r2), "=&v"(r3), "=&v"(r4), "=&v"(r5), "=&v"(r6),
              "=&v"(r7), "=&v"(r8), "=&v"(r9), "=&v"(rA), "=&v"(rB), "=&v"(rC), "=&v"(rD),
              "=&v"(rE), "=&v"(rF)
            : "v"(b0), "v"(b1), "v"(b2), "v"(b3));
        ACC4(r0, 0) ACC4(r1, 4) ACC4(r2, 8) ACC4(r3, 12)
        ACC4(r4, 0) ACC4(r5, 4) ACC4(r6, 8) ACC4(r7, 12)
        ACC4(r8, 0) ACC4(r9, 4) ACC4(rA, 8) ACC4(rB, 12)
        ACC4(rC, 0) ACC4(rD, 4) ACC4(rE, 8) ACC4(rF, 12)
      }
      for (; p < e_; ++p) {
        const float* b0 = va + (size_t)nzidx[p] * DIM + seg * 16;
        float4 r0, r1, r2, r3;
        asm volatile(
            "global_load_dwordx4 %0, %4, off sc0 sc1\n\t"
            "global_load_dwordx4 %1, %4, off offset:16 sc0 sc1\n\t"
            "global_load_dwordx4 %2, %4, off offset:32 sc0 sc1\n\t"
            "global_load_dwordx4 %3, %4, off offset:48 sc0 sc1\n\t"
            "s_waitcnt vmcnt(0)"
            : "=&v"(r0), "=&v"(r1), "=&v"(r2), "=&v"(r3)
            : "v"(b0));
        ACC4(r0, 0) ACC4(r1, 4) ACC4(r2, 8) ACC4(r3, 12)
      }
    }
    int k0 = seg * 16;
#pragma unroll
    for (int e = 0; e < 16; ++e) {
      int aidx = sw_idx(r, k0 + e);
      _Float16 hi = (_Float16)a[e];
      Xh[aidx] = hi;
      Xl[aidx] = (_Float16)(a[e] - (float)hi);
    }
  }
  __syncthreads();

  int lane = tid & 63, w = tid >> 6;
  int m = lane & 31, hf = lane >> 5;
  f32x16 acc[4];
#pragma unroll
  for (int g = 0; g < 4; ++g) {
    int col = (g << 7) + (w << 5) + (lane & 31);
    float bv = bih[col] + bhh[col];
#pragma unroll
    for (int i = 0; i < 16; ++i) acc[g][i] = bv;
  }
#pragma unroll
  for (int ks = 0; ks < 8; ++ks) {
    int a_off = (m << 7) + ((((ks * 2 + hf) ^ (m & 15))) << 3);
    half8 ah = *(const half8*)(Xh + a_off);
    half8 al = *(const half8*)(Xl + a_off);
#pragma unroll
    for (int g = 0; g < 4; ++g) {
      int nt = (g << 2) + w;
      int boff = ((nt * 8 + ks) * 64 + lane) * 8;
      half8 bh = *(const half8*)(Wxh + boff);
      half8 bl = *(const half8*)(Wxl + boff);
      acc[g] = __builtin_amdgcn_mfma_f32_32x32x16_f16(ah, bh, acc[g], 0, 0, 0);
      acc[g] = __builtin_amdgcn_mfma_f32_32x32x16_f16(ah, bl, acc[g], 0, 0, 0);
      acc[g] = __builtin_amdgcn_mfma_f32_32x32x16_f16(al, bh, acc[g], 0, 0, 0);
    }
  }
#pragma unroll
  for (int ks = 0; ks < 8; ++ks) {
    int a_off = (m << 7) + ((((ks * 2 + hf) ^ (m & 15))) << 3);
    half8 ah = *(const half8*)(Hh + a_off);
    half8 al = *(const half8*)(Hl + a_off);
#pragma unroll
    for (int g = 0; g < 4; ++g) {
      int nt = (g << 2) + w;
      int boff = ((nt * 8 + ks) * 64 + lane) * 8;
      half8 bh = *(const half8*)(Whh_ + boff);
      half8 bl = *(const half8*)(Whl + boff);
      acc[g] = __builtin_amdgcn_mfma_f32_32x32x16_f16(ah, bh, acc[g], 0, 0, 0);
      acc[g] = __builtin_amdgcn_mfma_f32_32x32x16_f16(ah, bl, acc[g], 0, 0, 0);
      acc[g] = __builtin_amdgcn_mfma_f32_32x32x16_f16(al, bh, acc[g], 0, 0, 0);
    }
  }
  int cw = (w << 5) + (lane & 31);
  int rbase = (lane >> 5) << 2;
#pragma unroll
  for (int reg = 0; reg < 16; ++reg) {
    int row = rb + (reg & 3) + ((reg >> 2) << 3) + rbase;
    if (row < M) {
      float iv = sigf(acc[0][reg]);
      float fv = sigf(acc[1][reg]);
      float gv = tanh_fast(acc[2][reg]);
      float ov = sigf(acc[3][reg]);
      size_t o = (size_t)row * DIM + cw;
      float cn = fv * cbuf[o] + iv * gv;   // cached: h/c rows are block-affine
      cbuf[o] = cn;
      hbuf[o] = ov * tanh_fast(cn);
    }
  }
}

// ---------------- grid barrier: relaxed atomics, no cache maintenance ----------------
// va traffic is sc0sc1 (L1/L2-bypass, memory-side coherent); h/c are block-affine cached;
// weights/indices immutable. Explicit vmcnt(0) drains each wave's bypass stores before arrival.
__device__ __forceinline__ void gbar(int* cnt, int* gen, int* my_gen) {
  asm volatile("s_waitcnt vmcnt(0)" ::: "memory");
  __syncthreads();
  if (threadIdx.x == 0) {
    int g = ++(*my_gen);
    int target = g * (int)gridDim.x;
    if (__hip_atomic_fetch_add(cnt, 1, __ATOMIC_RELAXED, __HIP_MEMORY_SCOPE_AGENT) + 1 == target) {
      __hip_atomic_store(gen, g, __ATOMIC_RELAXED, __HIP_MEMORY_SCOPE_AGENT);
    } else {
      int v;
      do {
        __builtin_amdgcn_s_sleep(8);
        v = __hip_atomic_load(gen, __ATOMIC_RELAXED, __HIP_MEMORY_SCOPE_AGENT);
      } while (v < g);
    }
  }
  __syncthreads();
}

// ---------------- persistent round-loop kernel ----------------
#define SZ128 (DIM * DIM)
#define SZ512 (4 * DIM * DIM)
#define O_CM1 0
#define O_CM2 (SZ128)
#define O_CM3 (2 * SZ128)
#define O_PM1 (3 * SZ128)
#define O_PM2 (4 * SZ128)
#define O_PM3 (5 * SZ128)
#define O_VUX (6 * SZ128)
#define O_VUH (6 * SZ128 + SZ512)
#define O_NUX (6 * SZ128 + 2 * SZ512)
#define O_NUH (6 * SZ128 + 3 * SZ512)

__global__ __launch_bounds__(256, 2) void persist_kernel(
    float* __restrict__ h, float* __restrict__ cb, float* __restrict__ va,
    const int* __restrict__ row_ptr, const int* __restrict__ col_idx,
    const int* __restrict__ col_ptr, const int* __restrict__ row_idx,
    const _Float16* __restrict__ ph, const _Float16* __restrict__ pl,
    const float* __restrict__ cm_b1, const float* __restrict__ cm_b2, const float* __restrict__ cm_b3,
    const float* __restrict__ pm_b1, const float* __restrict__ pm_b2, const float* __restrict__ pm_b3,
    const float* __restrict__ vu_bih, const float* __restrict__ vu_bhh,
    const float* __restrict__ nu_bih, const float* __restrict__ nu_bhh,
    int N, int n_nodes, int* bar_cnt, int* bar_gen) {
  __shared__ _Float16 S0[4096], S1[4096], S2[4096], S3[4096];
  int my_gen = 0;
  int tiles_N = (N + 31) >> 5;
  int tiles_n = (n_nodes + 31) >> 5;

  for (int r = 0; r < NROUNDS; ++r) {
    for (int t = blockIdx.x; t < tiles_N; t += gridDim.x)
      mlp_tile(h, N, t << 5, ph + O_CM1, pl + O_CM1, cm_b1, ph + O_CM2, pl + O_CM2, cm_b2,
               ph + O_CM3, pl + O_CM3, cm_b3, va, S0, S1, S2, S3);
    gbar(bar_cnt, bar_gen, &my_gen);
    for (int t = blockIdx.x; t < tiles_n; t += gridDim.x)
      lstm_tile(row_ptr, col_idx, va, h, cb, n_nodes, t << 5,
                ph + O_VUX, pl + O_VUX, ph + O_VUH, pl + O_VUH, vu_bih, vu_bhh,
                S0, S1, S2, S3);
    gbar(bar_cnt, bar_gen, &my_gen);
    for (int t = blockIdx.x; t < tiles_n; t += gridDim.x)
      mlp_tile(h, n_nodes, t << 5, ph + O_PM1, pl + O_PM1, pm_b1, ph + O_PM2, pl + O_PM2, pm_b2,
               ph + O_PM3, pl + O_PM3, pm_b3, va, S0, S1, S2, S3);
    gbar(bar_cnt, bar_gen, &my_gen);
    for (int t = blockIdx.x; t < tiles_N; t += gridDim.x)
      lstm_tile(col_ptr, row_idx, va, h, cb, N, t << 5,
                ph + O_NUX, pl + O_NUX, ph + O_NUH, pl + O_NUH, nu_bih, nu_bhh,
                S0, S1, S2, S3);
    gbar(bar_cnt, bar_gen, &my_gen);
  }
}

// ---------------- final vote MLP (fp32, runs once) ----------------
__device__ __forceinline__ void tile_gemm(const float* S, const float* __restrict__ W,
                                          int colB, int rowB, float acc[4][4]) {
#pragma unroll 4
  for (int kc = 0; kc < DIM; kc += 4) {
    float4 xv[4], wv[4];
#pragma unroll
    for (int r = 0; r < 4; ++r) xv[r] = *(const float4*)(S + (rowB + r) * DIM + kc);
#pragma unroll
    for (int c = 0; c < 4; ++c) wv[c] = *(const float4*)(W + (size_t)(colB + c) * DIM + kc);
#pragma unroll
    for (int r = 0; r < 4; ++r)
#pragma unroll
      for (int c = 0; c < 4; ++c)
        acc[r][c] += xv[r].x * wv[c].x + xv[r].y * wv[c].y + xv[r].z * wv[c].z + xv[r].w * wv[c].w;
  }
}

__device__ __forceinline__ void layer_lds(const float* Sin, float* Sout,
                                          const float* __restrict__ W, const float* __restrict__ B,
                                          bool relu, int colB, int rowB) {
  float acc[4][4];
#pragma unroll
  for (int r = 0; r < 4; ++r)
#pragma unroll
    for (int cc = 0; cc < 4; ++cc) acc[r][cc] = B[colB + cc];
  tile_gemm(Sin, W, colB, rowB, acc);
#pragma unroll
  for (int r = 0; r < 4; ++r) {
    float4 v;
    v.x = acc[r][0]; v.y = acc[r][1]; v.z = acc[r][2]; v.w = acc[r][3];
    if (relu) { v.x = fmaxf(v.x, 0.f); v.y = fmaxf(v.y, 0.f); v.z = fmaxf(v.z, 0.f); v.w = fmaxf(v.w, 0.f); }
    *(float4*)&Sout[(rowB + r) * DIM + colB] = v;
  }
  __syncthreads();
}

__global__ __launch_bounds__(256) void vote_kernel(
    const float* __restrict__ X, int M,
    const float* __restrict__ W1, const float* __restrict__ b1,
    const float* __restrict__ W2, const float* __restrict__ b2,
    const float* __restrict__ W3, const float* __restrict__ b3,
    float* __restrict__ out) {
  __shared__ float Xs[32 * DIM];
  __shared__ float Ys[32 * DIM];
  int tid = threadIdx.x;
  int rb = blockIdx.x * 32;
  int mrows = M - rb; if (mrows > 32) mrows = 32;
  {
    const float4* src = (const float4*)(X + (size_t)rb * DIM);
    float4* dst = (float4*)Xs;
    int nf4 = mrows * (DIM / 4);
    for (int t = tid; t < 32 * (DIM / 4); t += 256) {
      float4 v;
      if (t < nf4) v = src[t];
      else { v.x = v.y = v.z = v.w = 0.f; }
      dst[t] = v;
    }
  }
  __syncthreads();
  int tx = tid & 31, ty = tid >> 5;
  int colB = tx * 4, rowB = ty * 4;
  layer_lds(Xs, Ys, W1, b1, true, colB, rowB);
  layer_lds(Ys, Xs, W2, b2, true, colB, rowB);
  if (tid < 32) {
    int gr = rb + tid;
    if (gr < M) {
      float s = b3[0];
      for (int k = 0; k < DIM; ++k) s += Xs[tid * DIM + k] * W3[k];
      out[gr] = s;
    }
  }
}

extern "C" void kernel_launch(void* const* d_in, const int* in_sizes, int n_in,
                              void* d_out, int out_size, void* d_ws, size_t ws_size,
                              hipStream_t stream) {
  const float* adj    = (const float*)d_in[0];
  const int*   values = (const int*)d_in[1];
  const int N       = in_sizes[1];                  // 9000
  const int n_nodes = in_sizes[0] / N;              // 8000
  const int n_vars  = N - n_nodes;                  // 1000

  const float* true_W  = (const float*)d_in[3];
  const float* true_b  = (const float*)d_in[4];
  const float* false_W = (const float*)d_in[5];
  const float* false_b = (const float*)d_in[6];
  const float* cm_W1 = (const float*)d_in[7];
  const float* cm_b1 = (const float*)d_in[8];
  const float* cm_W2 = (const float*)d_in[9];
  const float* cm_b2 = (const float*)d_in[10];
  const float* cm_W3 = (const float*)d_in[11];
  const float* cm_b3 = (const float*)d_in[12];
  const float* pm_W1 = (const float*)d_in[13];
  const float* pm_b1 = (const float*)d_in[14];
  const float* pm_W2 = (const float*)d_in[15];
  const float* pm_b2 = (const float*)d_in[16];
  const float* pm_W3 = (const float*)d_in[17];
  const float* pm_b3 = (const float*)d_in[18];
  const float* vv_W1 = (const float*)d_in[19];
  const float* vv_b1 = (const float*)d_in[20];
  const float* vv_W2 = (const float*)d_in[21];
  const float* vv_b2 = (const float*)d_in[22];
  const float* vv_W3 = (const float*)d_in[23];
  const float* vv_b3 = (const float*)d_in[24];
  const float* vu_Wih = (const float*)d_in[25];
  const float* vu_Whh = (const float*)d_in[26];
  const float* vu_bih = (const float*)d_in[27];
  const float* vu_bhh = (const float*)d_in[28];
  const float* nu_Wih = (const float*)d_in[29];
  const float* nu_Whh = (const float*)d_in[30];
  const float* nu_bih = (const float*)d_in[31];
  const float* nu_bhh = (const float*)d_in[32];

  uintptr_t p = (uintptr_t)d_ws;
  auto take = [&](size_t bytes) -> void* {
    uintptr_t cur = (p + 255) & ~(uintptr_t)255;
    p = cur + bytes;
    return (void*)cur;
  };
  float* h  = (float*)take((size_t)N * DIM * sizeof(float));
  float* cb = (float*)take((size_t)N * DIM * sizeof(float));
  float* va = (float*)take((size_t)N * DIM * sizeof(float));
  int* row_ptr = (int*)take((size_t)(n_nodes + 1) * sizeof(int));
  int* col_ptr = (int*)take((size_t)(N + 1) * sizeof(int));
  int* cnts    = (int*)take((size_t)(n_nodes + N) * sizeof(int));
  int* row_cnt  = cnts;
  int* col_cnt  = cnts + n_nodes;
  int* col_idx = (int*)take((size_t)NNZ_CAP * sizeof(int));
  int* row_idx = (int*)take((size_t)NNZ_CAP * sizeof(int));
  int* bar = (int*)take(512);  // bar[0]=cnt, bar[64]=gen (separate lines)

  size_t tot_pack = (size_t)6 * SZ128 + (size_t)4 * SZ512;
  _Float16* packh = (_Float16*)take(tot_pack * sizeof(_Float16));
  _Float16* packl = (_Float16*)take(tot_pack * sizeof(_Float16));

  hipMemsetAsync(cnts, 0, (size_t)(n_nodes + N) * sizeof(int), stream);
  hipMemsetAsync(bar, 0, 512, stream);
  dim3 cgrid(n_nodes, (N + 255) / 256);
  count_nz_kernel<<<cgrid, 256, 0, stream>>>(adj, row_cnt, col_cnt, N);
  scan_kernel<<<1, 256, 0, stream>>>(row_cnt, row_ptr, n_nodes);
  scan_kernel<<<1, 256, 0, stream>>>(col_cnt, col_ptr, N);
  fill_csr_kernel<<<n_nodes, 64, 0, stream>>>(adj, row_ptr, col_idx, N);
  fill_csc_kernel<<<(N + 63) / 64, 64, 0, stream>>>(adj, col_ptr, row_idx, n_nodes, N);
  init_hc_kernel<<<(N * DIM + 255) / 256, 256, 0, stream>>>(values, true_W, true_b,
                                                            false_W, false_b, h, cb, N);

  auto pack = [&](const float* src, int out_dim, size_t o) {
    pack_w_kernel<<<(out_dim * DIM + 255) / 256, 256, 0, stream>>>(src, out_dim,
                                                                   packh + o, packl + o);
  };
  pack(cm_W1, DIM, O_CM1); pack(cm_W2, DIM, O_CM2); pack(cm_W3, DIM, O_CM3);
  pack(pm_W1, DIM, O_PM1); pack(pm_W2, DIM, O_PM2); pack(pm_W3, DIM, O_PM3);
  pack(vu_Wih, 4 * DIM, O_VUX); pack(vu_Whh, 4 * DIM, O_VUH);
  pack(nu_Wih, 4 * DIM, O_NUX); pack(nu_Whh, 4 * DIM, O_NUH);

  int nblocks = (N + 31) / 32;  // 282 blocks, all co-resident (2 blocks/CU capacity)
  persist_kernel<<<nblocks, 256, 0, stream>>>(
      h, cb, va, row_ptr, col_idx, col_ptr, row_idx, packh, packl,
      cm_b1, cm_b2, cm_b3, pm_b1, pm_b2, pm_b3,
      vu_bih, vu_bhh, nu_bih, nu_bhh, N, n_nodes, bar, bar + 64);

  vote_kernel<<<(n_vars + 31) / 32, 256, 0, stream>>>(h + (size_t)n_nodes * DIM, n_vars,
      vv_W1, vv_b1, vv_W2, vv_b2, vv_W3, vv_b3, (float*)d_out);
}

// Round 6
// 15489.751 us; speedup vs baseline: 4.3915x; 2.7750x over previous
//
#include <hip/hip_runtime.h>
#include <cstddef>
#include <cstdint>

#define DIM 128
#define NROUNDS 120
#define NNZ_CAP (1 << 20)

typedef _Float16 half8 __attribute__((ext_vector_type(8)));
typedef float f32x16 __attribute__((ext_vector_type(16)));
typedef unsigned long long u64;

__device__ __forceinline__ float sigf(float x) { return 1.f / (1.f + __expf(-x)); }
__device__ __forceinline__ float tanh_fast(float x) { return 2.f / (1.f + __expf(-2.f * x)) - 1.f; }

// ---------------- sparse build (deterministic) ----------------
__global__ void count_nz_kernel(const float* __restrict__ adj, int* __restrict__ row_cnt,
                                int* __restrict__ col_cnt, int ncols) {
  int i = blockIdx.x;
  int j = blockIdx.y * blockDim.x + threadIdx.x;
  bool nz = (j < ncols) && (adj[(size_t)i * ncols + j] != 0.f);
  unsigned long long m = __ballot(nz);
  if ((threadIdx.x & 63) == 0) {
    int c = __popcll(m);
    if (c) atomicAdd(&row_cnt[i], c);
  }
  if (nz) atomicAdd(&col_cnt[j], 1);  // count is order-independent -> deterministic
}

__global__ void scan_kernel(const int* __restrict__ cnt, int* __restrict__ ptr, int n) {
  __shared__ int sdata[256];
  int t = threadIdx.x;
  int per = (n + 255) / 256;
  int beg = t * per;
  int end = beg + per; if (end > n) end = n;
  int local = 0;
  for (int i = beg; i < end; ++i) local += cnt[i];
  sdata[t] = local;
  __syncthreads();
  for (int off = 1; off < 256; off <<= 1) {
    int v = (t >= off) ? sdata[t - off] : 0;
    __syncthreads();
    sdata[t] += v;
    __syncthreads();
  }
  int run = sdata[t] - local;
  for (int i = beg; i < end; ++i) { ptr[i] = run; run += cnt[i]; }
  if (t == 255) ptr[n] = sdata[255];
}

// deterministic CSR fill: one wave per row, ballot-prefix placement (ascending cols)
__global__ __launch_bounds__(64) void fill_csr_kernel(const float* __restrict__ adj,
                                                      const int* __restrict__ row_ptr,
                                                      int* __restrict__ col_idx, int ncols) {
  int row = blockIdx.x;
  int lane = threadIdx.x;
  int base = row_ptr[row];
  int cursor = 0;
  const float* arow = adj + (size_t)row * ncols;
  for (int j0 = 0; j0 < ncols; j0 += 64) {
    int j = j0 + lane;
    bool nz = (j < ncols) && (arow[j] != 0.f);
    u64 m = __ballot(nz);
    int pre = __popcll(m & ((1ull << lane) - 1));
    if (nz) col_idx[base + cursor + pre] = j;
    cursor += __popcll(m);
  }
}

// deterministic CSC fill: thread owns one column, scans rows ascending
__global__ __launch_bounds__(64) void fill_csc_kernel(const float* __restrict__ adj,
                                                      const int* __restrict__ col_ptr,
                                                      int* __restrict__ row_idx,
                                                      int nrows, int ncols) {
  int c = blockIdx.x * 64 + threadIdx.x;
  if (c >= ncols) return;
  int cur = col_ptr[c];
  for (int i = 0; i < nrows; ++i) {
    if (adj[(size_t)i * ncols + c] != 0.f) row_idx[cur++] = i;
  }
}

// ---------------- weight packing into MFMA B-fragment order (split f16) ----------------
__global__ void pack_w_kernel(const float* __restrict__ src, int out_dim,
                              _Float16* __restrict__ dh, _Float16* __restrict__ dl) {
  int idx = blockIdx.x * 256 + threadIdx.x;
  if (idx >= out_dim * DIM) return;
  int n = idx >> 7, k = idx & 127;
  float x = src[idx];
  _Float16 hi = (_Float16)x;
  _Float16 lo = (_Float16)(x - (float)hi);
  int nt = n >> 5, ks = k >> 4;
  int L = ((k >> 3) & 1) * 32 + (n & 31);
  int j = k & 7;
  int dst = ((nt * 8 + ks) * 64 + L) * 8 + j;
  dh[dst] = hi; dl[dst] = lo;
}

// ---------------- init ----------------
__global__ void init_hc_kernel(const int* __restrict__ values, const float* __restrict__ tW,
                               const float* __restrict__ tb, const float* __restrict__ fW,
                               const float* __restrict__ fb, float* __restrict__ h,
                               float* __restrict__ c, int N) {
  int idx = blockIdx.x * blockDim.x + threadIdx.x;
  if (idx >= N * DIM) return;
  int row = idx >> 7, col = idx & (DIM - 1);
  float tv = tW[col] + tb[col];
  float fv = fW[col] + fb[col];
  h[idx] = (values[row] == 1) ? tv : fv;
  c[idx] = 0.f;
}

// ---------------- LDS swizzle ----------------
__device__ __forceinline__ int sw_idx(int m, int k) {
  return (m << 7) + (((((k >> 3) ^ (m & 15))) << 3) | (k & 7));
}

// stage 32 fp32 rows (cached) -> split f16 LDS (MFMA A-layout)
__device__ __forceinline__ void stage_rows(const float* __restrict__ src, int M, int rb,
                                           _Float16* Sh, _Float16* Sl, int tid) {
  for (int t = tid; t < 32 * 32; t += 256) {
    int r = t >> 5, q = t & 31;
    int row = rb + r;
    float4 v;
    if (row < M) v = *(const float4*)(src + (size_t)row * DIM + q * 4);
    else { v.x = v.y = v.z = v.w = 0.f; }
    int a = sw_idx(r, q * 4);
    float vv[4] = {v.x, v.y, v.z, v.w};
#pragma unroll
    for (int e = 0; e < 4; ++e) {
      _Float16 hi = (_Float16)vv[e];
      Sh[a + e] = hi;
      Sl[a + e] = (_Float16)(vv[e] - (float)hi);
    }
  }
}

// deterministic binary-SpMM gather of 32 rows -> split f16 LDS (A-layout); cached loads
__device__ __forceinline__ void gather_rows(const int* __restrict__ ptr,
                                            const int* __restrict__ nzidx,
                                            const float* __restrict__ va, int M, int rb,
                                            _Float16* Xh, _Float16* Xl, int tid) {
  int r = tid >> 3, seg = tid & 7;
  int row = rb + r;
  float a[16];
#pragma unroll
  for (int e = 0; e < 16; ++e) a[e] = 0.f;
  if (row < M) {
    int s = ptr[row], e_ = ptr[row + 1];
    int p = s;
    for (; p + 4 <= e_; p += 4) {
      int i0 = nzidx[p], i1 = nzidx[p + 1], i2 = nzidx[p + 2], i3 = nzidx[p + 3];
      const float4* q0 = (const float4*)(va + (size_t)i0 * DIM + seg * 16);
      const float4* q1 = (const float4*)(va + (size_t)i1 * DIM + seg * 16);
      const float4* q2 = (const float4*)(va + (size_t)i2 * DIM + seg * 16);
      const float4* q3 = (const float4*)(va + (size_t)i3 * DIM + seg * 16);
      float4 w0[4], w1[4], w2[4], w3[4];
#pragma unroll
      for (int q = 0; q < 4; ++q) { w0[q] = q0[q]; w1[q] = q1[q]; w2[q] = q2[q]; w3[q] = q3[q]; }
#pragma unroll
      for (int q = 0; q < 4; ++q) {
        a[q * 4 + 0] += (w0[q].x + w1[q].x) + (w2[q].x + w3[q].x);
        a[q * 4 + 1] += (w0[q].y + w1[q].y) + (w2[q].y + w3[q].y);
        a[q * 4 + 2] += (w0[q].z + w1[q].z) + (w2[q].z + w3[q].z);
        a[q * 4 + 3] += (w0[q].w + w1[q].w) + (w2[q].w + w3[q].w);
      }
    }
    for (; p < e_; ++p) {
      const float* src = va + (size_t)nzidx[p] * DIM + seg * 16;
#pragma unroll
      for (int q = 0; q < 4; ++q) {
        float4 v = *(const float4*)(src + q * 4);
        a[q * 4 + 0] += v.x; a[q * 4 + 1] += v.y;
        a[q * 4 + 2] += v.z; a[q * 4 + 3] += v.w;
      }
    }
  }
  int k0 = seg * 16;
#pragma unroll
  for (int e = 0; e < 16; ++e) {
    int aidx = sw_idx(r, k0 + e);
    _Float16 hi = (_Float16)a[e];
    Xh[aidx] = hi;
    Xl[aidx] = (_Float16)(a[e] - (float)hi);
  }
}

// one 32x32 output tile over K=128, split-f16, dual accumulator chains
__device__ __forceinline__ f32x16 gemm_tile(const _Float16* Sh, const _Float16* Sl,
                                            const _Float16* __restrict__ Bh,
                                            const _Float16* __restrict__ Bl,
                                            int nt, int lane, f32x16 acc) {
  int m = lane & 31, hf = lane >> 5;
  f32x16 acc2;
#pragma unroll
  for (int i = 0; i < 16; ++i) acc2[i] = 0.f;
#pragma unroll
  for (int ks = 0; ks < 8; ++ks) {
    int a_off = (m << 7) + ((((ks * 2 + hf) ^ (m & 15))) << 3);
    half8 ah = *(const half8*)(Sh + a_off);
    half8 al = *(const half8*)(Sl + a_off);
    int boff = ((nt * 8 + ks) * 64 + lane) * 8;
    half8 bh = *(const half8*)(Bh + boff);
    half8 bl = *(const half8*)(Bl + boff);
    f32x16& A = (ks & 1) ? acc2 : acc;
    A = __builtin_amdgcn_mfma_f32_32x32x16_f16(ah, bh, A, 0, 0, 0);
    A = __builtin_amdgcn_mfma_f32_32x32x16_f16(ah, bl, A, 0, 0, 0);
    A = __builtin_amdgcn_mfma_f32_32x32x16_f16(al, bh, A, 0, 0, 0);
  }
#pragma unroll
  for (int i = 0; i < 16; ++i) acc[i] += acc2[i];
  return acc;
}

// C/D layout (col=lane&31, row=(reg&3)+8*(reg>>2)+4*(lane>>5)) -> split f16 LDS (A-layout)
__device__ __forceinline__ void write_cd_lds(f32x16 acc, _Float16* Dh, _Float16* Dl,
                                             int nt, int lane, bool relu) {
  int col = (nt << 5) + (lane & 31);
  int rbase = (lane >> 5) << 2;
#pragma unroll
  for (int reg = 0; reg < 16; ++reg) {
    int row = (reg & 3) + ((reg >> 2) << 3) + rbase;
    float x = acc[reg];
    if (relu) x = fmaxf(x, 0.f);
    _Float16 hi = (_Float16)x;
    int a = sw_idx(row, col);
    Dh[a] = hi;
    Dl[a] = (_Float16)(x - (float)hi);
  }
}

// MLP over LDS input (S0/S1), scratch (S2/S3), final layer -> cached global stores
__device__ __forceinline__ void mlp_from_lds(
    _Float16* S0, _Float16* S1, _Float16* S2, _Float16* S3, int M, int rb,
    const _Float16* __restrict__ W1h, const _Float16* __restrict__ W1l, const float* __restrict__ b1,
    const _Float16* __restrict__ W2h, const _Float16* __restrict__ W2l, const float* __restrict__ b2,
    const _Float16* __restrict__ W3h, const _Float16* __restrict__ W3l, const float* __restrict__ b3,
    float* __restrict__ out) {
  int tid = threadIdx.x;
  int lane = tid & 63, w = tid >> 6;
  int colw = (w << 5) + (lane & 31);
  f32x16 acc;
  float bv;

  bv = b1[colw];
#pragma unroll
  for (int i = 0; i < 16; ++i) acc[i] = bv;
  acc = gemm_tile(S0, S1, W1h, W1l, w, lane, acc);
  write_cd_lds(acc, S2, S3, w, lane, true);
  __syncthreads();

  bv = b2[colw];
#pragma unroll
  for (int i = 0; i < 16; ++i) acc[i] = bv;
  acc = gemm_tile(S2, S3, W2h, W2l, w, lane, acc);
  write_cd_lds(acc, S0, S1, w, lane, true);
  __syncthreads();

  bv = b3[colw];
#pragma unroll
  for (int i = 0; i < 16; ++i) acc[i] = bv;
  acc = gemm_tile(S0, S1, W3h, W3l, w, lane, acc);

  int rbase = (lane >> 5) << 2;
#pragma unroll
  for (int reg = 0; reg < 16; ++reg) {
    int row = rb + (reg & 3) + ((reg >> 2) << 3) + rbase;
    if (row < M) out[(size_t)row * DIM + colw] = acc[reg];
  }
}

// ---------------- standalone MLP (initial phase A): global h -> va ----------------
__global__ __launch_bounds__(256) void mlp3_mfma(
    const float* __restrict__ X, int M,
    const _Float16* __restrict__ W1h, const _Float16* __restrict__ W1l, const float* __restrict__ b1,
    const _Float16* __restrict__ W2h, const _Float16* __restrict__ W2l, const float* __restrict__ b2,
    const _Float16* __restrict__ W3h, const _Float16* __restrict__ W3l, const float* __restrict__ b3,
    float* __restrict__ out) {
  __shared__ _Float16 S0[4096], S1[4096], S2[4096], S3[4096];
  int tid = threadIdx.x;
  int rb = blockIdx.x << 5;
  stage_rows(X, M, rb, S0, S1, tid);
  __syncthreads();
  mlp_from_lds(S0, S1, S2, S3, M, rb, W1h, W1l, b1, W2h, W2l, b2, W3h, W3l, b3, out);
}

// ---------------- fused LSTM (+ optional row-local MLP): va_in -> h,c [-> va_out] ----------------
template <bool DO_MLP>
__global__ __launch_bounds__(256) void lstm_fused(
    const int* __restrict__ ptr, const int* __restrict__ nzidx, const float* __restrict__ va_in,
    float* __restrict__ hbuf, float* __restrict__ cbuf, int M,
    const _Float16* __restrict__ Wxh, const _Float16* __restrict__ Wxl,
    const _Float16* __restrict__ Whh_, const _Float16* __restrict__ Whl,
    const float* __restrict__ bih, const float* __restrict__ bhh,
    const _Float16* __restrict__ W1h, const _Float16* __restrict__ W1l, const float* __restrict__ b1,
    const _Float16* __restrict__ W2h, const _Float16* __restrict__ W2l, const float* __restrict__ b2,
    const _Float16* __restrict__ W3h, const _Float16* __restrict__ W3l, const float* __restrict__ b3,
    float* __restrict__ va_out) {
  __shared__ _Float16 Xh[4096], Xl[4096], Hh[4096], Hl[4096];
  int tid = threadIdx.x;
  int rb = blockIdx.x << 5;
  stage_rows(hbuf, M, rb, Hh, Hl, tid);
  gather_rows(ptr, nzidx, va_in, M, rb, Xh, Xl, tid);
  __syncthreads();

  int lane = tid & 63, w = tid >> 6;
  int m = lane & 31, hf = lane >> 5;
  f32x16 acc[4];
#pragma unroll
  for (int g = 0; g < 4; ++g) {
    int col = (g << 7) + (w << 5) + (lane & 31);
    float bv = bih[col] + bhh[col];
#pragma unroll
    for (int i = 0; i < 16; ++i) acc[g][i] = bv;
  }
#pragma unroll
  for (int ks = 0; ks < 8; ++ks) {
    int a_off = (m << 7) + ((((ks * 2 + hf) ^ (m & 15))) << 3);
    half8 ah = *(const half8*)(Xh + a_off);
    half8 al = *(const half8*)(Xl + a_off);
#pragma unroll
    for (int g = 0; g < 4; ++g) {
      int nt = (g << 2) + w;
      int boff = ((nt * 8 + ks) * 64 + lane) * 8;
      half8 bh = *(const half8*)(Wxh + boff);
      half8 bl = *(const half8*)(Wxl + boff);
      acc[g] = __builtin_amdgcn_mfma_f32_32x32x16_f16(ah, bh, acc[g], 0, 0, 0);
      acc[g] = __builtin_amdgcn_mfma_f32_32x32x16_f16(ah, bl, acc[g], 0, 0, 0);
      acc[g] = __builtin_amdgcn_mfma_f32_32x32x16_f16(al, bh, acc[g], 0, 0, 0);
    }
  }
#pragma unroll
  for (int ks = 0; ks < 8; ++ks) {
    int a_off = (m << 7) + ((((ks * 2 + hf) ^ (m & 15))) << 3);
    half8 ah = *(const half8*)(Hh + a_off);
    half8 al = *(const half8*)(Hl + a_off);
#pragma unroll
    for (int g = 0; g < 4; ++g) {
      int nt = (g << 2) + w;
      int boff = ((nt * 8 + ks) * 64 + lane) * 8;
      half8 bh = *(const half8*)(Whh_ + boff);
      half8 bl = *(const half8*)(Whl + boff);
      acc[g] = __builtin_amdgcn_mfma_f32_32x32x16_f16(ah, bh, acc[g], 0, 0, 0);
      acc[g] = __builtin_amdgcn_mfma_f32_32x32x16_f16(ah, bl, acc[g], 0, 0, 0);
      acc[g] = __builtin_amdgcn_mfma_f32_32x32x16_f16(al, bh, acc[g], 0, 0, 0);
    }
  }

  if (DO_MLP) __syncthreads();  // all waves done reading Xh/Xl/Hh/Hl before overwrite

  // elementwise epilogue: gate order i,f,g,o ; h,c -> global (owner rows), h_new -> LDS
  int cw = (w << 5) + (lane & 31);
  int rbase = (lane >> 5) << 2;
#pragma unroll
  for (int reg = 0; reg < 16; ++reg) {
    int rl = (reg & 3) + ((reg >> 2) << 3) + rbase;
    int row = rb + rl;
    float hn = 0.f;
    if (row < M) {
      float iv = sigf(acc[0][reg]);
      float fv = sigf(acc[1][reg]);
      float gv = tanh_fast(acc[2][reg]);
      float ov = sigf(acc[3][reg]);
      size_t o = (size_t)row * DIM + cw;
      float cn = fv * cbuf[o] + iv * gv;
      cbuf[o] = cn;
      hn = ov * tanh_fast(cn);
      hbuf[o] = hn;
    }
    if (DO_MLP) {
      int a = sw_idx(rl, cw);
      _Float16 hi = (_Float16)hn;
      Xh[a] = hi;
      Xl[a] = (_Float16)(hn - (float)hi);
    }
  }
  if (DO_MLP) {
    __syncthreads();
    mlp_from_lds(Xh, Xl, Hh, Hl, M, rb, W1h, W1l, b1, W2h, W2l, b2, W3h, W3l, b3, va_out);
  }
}

// ---------------- final vote MLP (fp32, runs once) ----------------
__device__ __forceinline__ void tile_gemm(const float* S, const float* __restrict__ W,
                                          int colB, int rowB, float acc[4][4]) {
#pragma unroll 4
  for (int kc = 0; kc < DIM; kc += 4) {
    float4 xv[4], wv[4];
#pragma unroll
    for (int r = 0; r < 4; ++r) xv[r] = *(const float4*)(S + (rowB + r) * DIM + kc);
#pragma unroll
    for (int c = 0; c < 4; ++c) wv[c] = *(const float4*)(W + (size_t)(colB + c) * DIM + kc);
#pragma unroll
    for (int r = 0; r < 4; ++r)
#pragma unroll
      for (int c = 0; c < 4; ++c)
        acc[r][c] += xv[r].x * wv[c].x + xv[r].y * wv[c].y + xv[r].z * wv[c].z + xv[r].w * wv[c].w;
  }
}

__device__ __forceinline__ void layer_lds(const float* Sin, float* Sout,
                                          const float* __restrict__ W, const float* __restrict__ B,
                                          bool relu, int colB, int rowB) {
  float acc[4][4];
#pragma unroll
  for (int r = 0; r < 4; ++r)
#pragma unroll
    for (int cc = 0; cc < 4; ++cc) acc[r][cc] = B[colB + cc];
  tile_gemm(Sin, W, colB, rowB, acc);
#pragma unroll
  for (int r = 0; r < 4; ++r) {
    float4 v;
    v.x = acc[r][0]; v.y = acc[r][1]; v.z = acc[r][2]; v.w = acc[r][3];
    if (relu) { v.x = fmaxf(v.x, 0.f); v.y = fmaxf(v.y, 0.f); v.z = fmaxf(v.z, 0.f); v.w = fmaxf(v.w, 0.f); }
    *(float4*)&Sout[(rowB + r) * DIM + colB] = v;
  }
  __syncthreads();
}

__global__ __launch_bounds__(256) void vote_kernel(
    const float* __restrict__ X, int M,
    const float* __restrict__ W1, const float* __restrict__ b1,
    const float* __restrict__ W2, const float* __restrict__ b2,
    const float* __restrict__ W3, const float* __restrict__ b3,
    float* __restrict__ out) {
  __shared__ float Xs[32 * DIM];
  __shared__ float Ys[32 * DIM];
  int tid = threadIdx.x;
  int rb = blockIdx.x * 32;
  int mrows = M - rb; if (mrows > 32) mrows = 32;
  {
    const float4* src = (const float4*)(X + (size_t)rb * DIM);
    float4* dst = (float4*)Xs;
    int nf4 = mrows * (DIM / 4);
    for (int t = tid; t < 32 * (DIM / 4); t += 256) {
      float4 v;
      if (t < nf4) v = src[t];
      else { v.x = v.y = v.z = v.w = 0.f; }
      dst[t] = v;
    }
  }
  __syncthreads();
  int tx = tid & 31, ty = tid >> 5;
  int colB = tx * 4, rowB = ty * 4;
  layer_lds(Xs, Ys, W1, b1, true, colB, rowB);
  layer_lds(Ys, Xs, W2, b2, true, colB, rowB);
  if (tid < 32) {
    int gr = rb + tid;
    if (gr < M) {
      float s = b3[0];
      for (int k = 0; k < DIM; ++k) s += Xs[tid * DIM + k] * W3[k];
      out[gr] = s;
    }
  }
}

#define SZ128 (DIM * DIM)
#define SZ512 (4 * DIM * DIM)
#define O_CM1 0
#define O_CM2 (SZ128)
#define O_CM3 (2 * SZ128)
#define O_PM1 (3 * SZ128)
#define O_PM2 (4 * SZ128)
#define O_PM3 (5 * SZ128)
#define O_VUX ((size_t)6 * SZ128)
#define O_VUH ((size_t)6 * SZ128 + SZ512)
#define O_NUX ((size_t)6 * SZ128 + 2 * SZ512)
#define O_NUH ((size_t)6 * SZ128 + 3 * SZ512)

extern "C" void kernel_launch(void* const* d_in, const int* in_sizes, int n_in,
                              void* d_out, int out_size, void* d_ws, size_t ws_size,
                              hipStream_t stream) {
  const float* adj    = (const float*)d_in[0];
  const int*   values = (const int*)d_in[1];
  const int N       = in_sizes[1];                  // 9000
  const int n_nodes = in_sizes[0] / N;              // 8000
  const int n_vars  = N - n_nodes;                  // 1000

  const float* true_W  = (const float*)d_in[3];
  const float* true_b  = (const float*)d_in[4];
  const float* false_W = (const float*)d_in[5];
  const float* false_b = (const float*)d_in[6];
  const float* cm_W1 = (const float*)d_in[7];
  const float* cm_b1 = (const float*)d_in[8];
  const float* cm_W2 = (const float*)d_in[9];
  const float* cm_b2 = (const float*)d_in[10];
  const float* cm_W3 = (const float*)d_in[11];
  const float* cm_b3 = (const float*)d_in[12];
  const float* pm_W1 = (const float*)d_in[13];
  const float* pm_b1 = (const float*)d_in[14];
  const float* pm_W2 = (const float*)d_in[15];
  const float* pm_b2 = (const float*)d_in[16];
  const float* pm_W3 = (const float*)d_in[17];
  const float* pm_b3 = (const float*)d_in[18];
  const float* vv_W1 = (const float*)d_in[19];
  const float* vv_b1 = (const float*)d_in[20];
  const float* vv_W2 = (const float*)d_in[21];
  const float* vv_b2 = (const float*)d_in[22];
  const float* vv_W3 = (const float*)d_in[23];
  const float* vv_b3 = (const float*)d_in[24];
  const float* vu_Wih = (const float*)d_in[25];
  const float* vu_Whh = (const float*)d_in[26];
  const float* vu_bih = (const float*)d_in[27];
  const float* vu_bhh = (const float*)d_in[28];
  const float* nu_Wih = (const float*)d_in[29];
  const float* nu_Whh = (const float*)d_in[30];
  const float* nu_bih = (const float*)d_in[31];
  const float* nu_bhh = (const float*)d_in[32];

  uintptr_t p = (uintptr_t)d_ws;
  auto take = [&](size_t bytes) -> void* {
    uintptr_t cur = (p + 255) & ~(uintptr_t)255;
    p = cur + bytes;
    return (void*)cur;
  };
  float* h   = (float*)take((size_t)N * DIM * sizeof(float));
  float* cb  = (float*)take((size_t)N * DIM * sizeof(float));
  float* va1 = (float*)take((size_t)N * DIM * sizeof(float));
  float* va2 = (float*)take((size_t)N * DIM * sizeof(float));
  int* row_ptr = (int*)take((size_t)(n_nodes + 1) * sizeof(int));
  int* col_ptr = (int*)take((size_t)(N + 1) * sizeof(int));
  int* cnts    = (int*)take((size_t)(n_nodes + N) * sizeof(int));
  int* row_cnt = cnts;
  int* col_cnt = cnts + n_nodes;
  int* col_idx = (int*)take((size_t)NNZ_CAP * sizeof(int));
  int* row_idx = (int*)take((size_t)NNZ_CAP * sizeof(int));

  size_t tot_pack = (size_t)6 * SZ128 + (size_t)4 * SZ512;
  _Float16* packh = (_Float16*)take(tot_pack * sizeof(_Float16));
  _Float16* packl = (_Float16*)take(tot_pack * sizeof(_Float16));

  hipMemsetAsync(cnts, 0, (size_t)(n_nodes + N) * sizeof(int), stream);
  dim3 cgrid(n_nodes, (N + 255) / 256);
  count_nz_kernel<<<cgrid, 256, 0, stream>>>(adj, row_cnt, col_cnt, N);
  scan_kernel<<<1, 256, 0, stream>>>(row_cnt, row_ptr, n_nodes);
  scan_kernel<<<1, 256, 0, stream>>>(col_cnt, col_ptr, N);
  fill_csr_kernel<<<n_nodes, 64, 0, stream>>>(adj, row_ptr, col_idx, N);
  fill_csc_kernel<<<(N + 63) / 64, 64, 0, stream>>>(adj, col_ptr, row_idx, n_nodes, N);
  init_hc_kernel<<<(N * DIM + 255) / 256, 256, 0, stream>>>(values, true_W, true_b,
                                                            false_W, false_b, h, cb, N);

  auto pack = [&](const float* src, int out_dim, size_t o) {
    pack_w_kernel<<<(out_dim * DIM + 255) / 256, 256, 0, stream>>>(src, out_dim,
                                                                   packh + o, packl + o);
  };
  pack(cm_W1, DIM, O_CM1); pack(cm_W2, DIM, O_CM2); pack(cm_W3, DIM, O_CM3);
  pack(pm_W1, DIM, O_PM1); pack(pm_W2, DIM, O_PM2); pack(pm_W3, DIM, O_PM3);
  pack(vu_Wih, 4 * DIM, O_VUX); pack(vu_Whh, 4 * DIM, O_VUH);
  pack(nu_Wih, 4 * DIM, O_NUX); pack(nu_Whh, 4 * DIM, O_NUH);

  int tiles_N = (N + 31) / 32, tiles_n = (n_nodes + 31) / 32;

  // A0: var_pre = cm_mlp(h) -> va1
  mlp3_mfma<<<tiles_N, 256, 0, stream>>>(h, N,
      packh + O_CM1, packl + O_CM1, cm_b1,
      packh + O_CM2, packl + O_CM2, cm_b2,
      packh + O_CM3, packl + O_CM3, cm_b3, va1);

  for (int r = 0; r < NROUNDS; ++r) {
    // B+C: vu-LSTM(csr-gather va1) on rows<n_nodes, then pm-MLP(h_new) -> va2
    lstm_fused<true><<<tiles_n, 256, 0, stream>>>(row_ptr, col_idx, va1, h, cb, n_nodes,
        packh + O_VUX, packl + O_VUX, packh + O_VUH, packl + O_VUH, vu_bih, vu_bhh,
        packh + O_PM1, packl + O_PM1, pm_b1,
        packh + O_PM2, packl + O_PM2, pm_b2,
        packh + O_PM3, packl + O_PM3, pm_b3, va2);
    if (r + 1 < NROUNDS) {
      // D+A(next): nu-LSTM(csc-gather va2) on all N rows, then cm-MLP(h_new) -> va1
      lstm_fused<true><<<tiles_N, 256, 0, stream>>>(col_ptr, row_idx, va2, h, cb, N,
          packh + O_NUX, packl + O_NUX, packh + O_NUH, packl + O_NUH, nu_bih, nu_bhh,
          packh + O_CM1, packl + O_CM1, cm_b1,
          packh + O_CM2, packl + O_CM2, cm_b2,
          packh + O_CM3, packl + O_CM3, cm_b3, va1);
    } else {
      // final D: nu-LSTM only
      lstm_fused<false><<<tiles_N, 256, 0, stream>>>(col_ptr, row_idx, va2, h, cb, N,
          packh + O_NUX, packl + O_NUX, packh + O_NUH, packl + O_NUH, nu_bih, nu_bhh,
          packh + O_CM1, packl + O_CM1, cm_b1,
          packh + O_CM2, packl + O_CM2, cm_b2,
          packh + O_CM3, packl + O_CM3, cm_b3, va1);
    }
  }

  vote_kernel<<<(n_vars + 31) / 32, 256, 0, stream>>>(h + (size_t)n_nodes * DIM, n_vars,
      vv_W1, vv_b1, vv_W2, vv_b2, vv_W3, vv_b3, (float*)d_out);
}

// Round 7
// 13380.475 us; speedup vs baseline: 5.0838x; 1.1576x over previous
//
#include <hip/hip_runtime.h>
#include <cstddef>
#include <cstdint>

#define DIM 128
#define NROUNDS 120
#define NNZ_CAP (1 << 20)

typedef _Float16 half8 __attribute__((ext_vector_type(8)));
typedef float f32x4 __attribute__((ext_vector_type(4)));
typedef unsigned long long u64;

__device__ __forceinline__ float sigf(float x) { return 1.f / (1.f + __expf(-x)); }
__device__ __forceinline__ float tanh_fast(float x) { return 2.f / (1.f + __expf(-2.f * x)) - 1.f; }

// ---------------- sparse build (deterministic) ----------------
__global__ void count_nz_kernel(const float* __restrict__ adj, int* __restrict__ row_cnt,
                                int* __restrict__ col_cnt, int ncols) {
  int i = blockIdx.x;
  int j = blockIdx.y * blockDim.x + threadIdx.x;
  bool nz = (j < ncols) && (adj[(size_t)i * ncols + j] != 0.f);
  unsigned long long m = __ballot(nz);
  if ((threadIdx.x & 63) == 0) {
    int c = __popcll(m);
    if (c) atomicAdd(&row_cnt[i], c);
  }
  if (nz) atomicAdd(&col_cnt[j], 1);
}

__global__ void scan_kernel(const int* __restrict__ cnt, int* __restrict__ ptr, int n) {
  __shared__ int sdata[256];
  int t = threadIdx.x;
  int per = (n + 255) / 256;
  int beg = t * per;
  int end = beg + per; if (end > n) end = n;
  int local = 0;
  for (int i = beg; i < end; ++i) local += cnt[i];
  sdata[t] = local;
  __syncthreads();
  for (int off = 1; off < 256; off <<= 1) {
    int v = (t >= off) ? sdata[t - off] : 0;
    __syncthreads();
    sdata[t] += v;
    __syncthreads();
  }
  int run = sdata[t] - local;
  for (int i = beg; i < end; ++i) { ptr[i] = run; run += cnt[i]; }
  if (t == 255) ptr[n] = sdata[255];
}

__global__ __launch_bounds__(64) void fill_csr_kernel(const float* __restrict__ adj,
                                                      const int* __restrict__ row_ptr,
                                                      int* __restrict__ col_idx, int ncols) {
  int row = blockIdx.x;
  int lane = threadIdx.x;
  int base = row_ptr[row];
  int cursor = 0;
  const float* arow = adj + (size_t)row * ncols;
  for (int j0 = 0; j0 < ncols; j0 += 64) {
    int j = j0 + lane;
    bool nz = (j < ncols) && (arow[j] != 0.f);
    u64 m = __ballot(nz);
    int pre = __popcll(m & ((1ull << lane) - 1));
    if (nz) col_idx[base + cursor + pre] = j;
    cursor += __popcll(m);
  }
}

__global__ __launch_bounds__(64) void fill_csc_kernel(const float* __restrict__ adj,
                                                      const int* __restrict__ col_ptr,
                                                      int* __restrict__ row_idx,
                                                      int nrows, int ncols) {
  int c = blockIdx.x * 64 + threadIdx.x;
  if (c >= ncols) return;
  int cur = col_ptr[c];
  for (int i = 0; i < nrows; ++i) {
    if (adj[(size_t)i * ncols + c] != 0.f) row_idx[cur++] = i;
  }
}

// ---------------- weight packing: MFMA 16x16x32 B-fragment order (split f16) ----------------
// B[k][n] = W[n][k]; lane L holds n = L&15, k = ks*32 + (L>>4)*8 + j (j=0..7)
// dst = ((nt*4 + ks)*64 + L)*8 + j, nt = n>>4
__global__ void pack_w_kernel(const float* __restrict__ src, int out_dim,
                              _Float16* __restrict__ dh, _Float16* __restrict__ dl) {
  int idx = blockIdx.x * 256 + threadIdx.x;
  if (idx >= out_dim * DIM) return;
  int n = idx >> 7, k = idx & 127;
  float x = src[idx];
  _Float16 hi = (_Float16)x;
  _Float16 lo = (_Float16)(x - (float)hi);
  int nt = n >> 4, ks = k >> 5;
  int L = ((k >> 3) & 3) * 16 + (n & 15);
  int j = k & 7;
  int dst = ((nt * 4 + ks) * 64 + L) * 8 + j;
  dh[dst] = hi; dl[dst] = lo;
}

// ---------------- init ----------------
__global__ void init_hc_kernel(const int* __restrict__ values, const float* __restrict__ tW,
                               const float* __restrict__ tb, const float* __restrict__ fW,
                               const float* __restrict__ fb, float* __restrict__ h,
                               float* __restrict__ c, int N) {
  int idx = blockIdx.x * blockDim.x + threadIdx.x;
  if (idx >= N * DIM) return;
  int row = idx >> 7, col = idx & (DIM - 1);
  float tv = tW[col] + tb[col];
  float fv = fW[col] + fb[col];
  h[idx] = (values[row] == 1) ? tv : fv;
  c[idx] = 0.f;
}

// ---------------- LDS swizzle (32 rows x 128, 8-chunk XOR) ----------------
__device__ __forceinline__ int sw_idx(int m, int k) {
  return (m << 7) + (((((k >> 3) ^ (m & 15))) << 3) | (k & 7));
}

// stage 32 fp32 rows -> split f16 LDS (512 threads: r=tid>>4, 8 floats each)
__device__ __forceinline__ void stage_rows(const float* __restrict__ src, int M, int rb,
                                           _Float16* Sh, _Float16* Sl, int tid) {
  int r = tid >> 4, q = tid & 15;
  int row = rb + r;
  float4 v0, v1;
  if (row < M) {
    const float4* s = (const float4*)(src + (size_t)row * DIM + q * 8);
    v0 = s[0]; v1 = s[1];
  } else {
    v0.x = v0.y = v0.z = v0.w = 0.f; v1 = v0;
  }
  int a = sw_idx(r, q * 8);
  float vv[8] = {v0.x, v0.y, v0.z, v0.w, v1.x, v1.y, v1.z, v1.w};
#pragma unroll
  for (int e = 0; e < 8; ++e) {
    _Float16 hi = (_Float16)vv[e];
    Sh[a + e] = hi;
    Sl[a + e] = (_Float16)(vv[e] - (float)hi);
  }
}

// deterministic binary-SpMM gather of 32 rows -> split f16 LDS (512 threads)
__device__ __forceinline__ void gather_rows(const int* __restrict__ ptr,
                                            const int* __restrict__ nzidx,
                                            const float* __restrict__ va, int M, int rb,
                                            _Float16* Xh, _Float16* Xl, int tid) {
  int r = tid >> 4, seg = tid & 15;
  int row = rb + r;
  float a[8];
#pragma unroll
  for (int e = 0; e < 8; ++e) a[e] = 0.f;
  if (row < M) {
    int s = ptr[row], e_ = ptr[row + 1];
    int p = s;
    for (; p + 4 <= e_; p += 4) {
      int i0 = nzidx[p], i1 = nzidx[p + 1], i2 = nzidx[p + 2], i3 = nzidx[p + 3];
      const float4* q0 = (const float4*)(va + (size_t)i0 * DIM + seg * 8);
      const float4* q1 = (const float4*)(va + (size_t)i1 * DIM + seg * 8);
      const float4* q2 = (const float4*)(va + (size_t)i2 * DIM + seg * 8);
      const float4* q3 = (const float4*)(va + (size_t)i3 * DIM + seg * 8);
      float4 w0[2], w1[2], w2[2], w3[2];
#pragma unroll
      for (int q = 0; q < 2; ++q) { w0[q] = q0[q]; w1[q] = q1[q]; w2[q] = q2[q]; w3[q] = q3[q]; }
#pragma unroll
      for (int q = 0; q < 2; ++q) {
        a[q * 4 + 0] += (w0[q].x + w1[q].x) + (w2[q].x + w3[q].x);
        a[q * 4 + 1] += (w0[q].y + w1[q].y) + (w2[q].y + w3[q].y);
        a[q * 4 + 2] += (w0[q].z + w1[q].z) + (w2[q].z + w3[q].z);
        a[q * 4 + 3] += (w0[q].w + w1[q].w) + (w2[q].w + w3[q].w);
      }
    }
    for (; p < e_; ++p) {
      const float4* q0 = (const float4*)(va + (size_t)nzidx[p] * DIM + seg * 8);
#pragma unroll
      for (int q = 0; q < 2; ++q) {
        float4 v = q0[q];
        a[q * 4 + 0] += v.x; a[q * 4 + 1] += v.y;
        a[q * 4 + 2] += v.z; a[q * 4 + 3] += v.w;
      }
    }
  }
  int aoff = sw_idx(r, seg * 8);
#pragma unroll
  for (int e = 0; e < 8; ++e) {
    _Float16 hi = (_Float16)a[e];
    Xh[aoff + e] = hi;
    Xl[aoff + e] = (_Float16)(a[e] - (float)hi);
  }
}

__device__ __forceinline__ void mfma3(f32x4& acc, half8 ah, half8 al, half8 bh, half8 bl) {
  acc = __builtin_amdgcn_mfma_f32_16x16x32_f16(ah, bh, acc, 0, 0, 0);
  acc = __builtin_amdgcn_mfma_f32_16x16x32_f16(ah, bl, acc, 0, 0, 0);
  acc = __builtin_amdgcn_mfma_f32_16x16x32_f16(al, bh, acc, 0, 0, 0);
}

// one MLP layer: LDS A (32x128 split) -> wave (sub,ww) computes 16x32 -> LDS D; trailing sync
__device__ __forceinline__ void mlp_layer(const _Float16* Ah_, const _Float16* Al_,
                                          const _Float16* __restrict__ Wh,
                                          const _Float16* __restrict__ Wl,
                                          const float* __restrict__ B,
                                          _Float16* Dh, _Float16* Dl, int tid) {
  int lane = tid & 63, w = tid >> 6, sub = w >> 2, ww = w & 3;
  int m16 = lane & 15, quad = lane >> 4;
  f32x4 acc[2];
#pragma unroll
  for (int c2 = 0; c2 < 2; ++c2) {
    float bv = B[ww * 32 + c2 * 16 + m16];
    acc[c2] = (f32x4){bv, bv, bv, bv};
  }
#pragma unroll
  for (int ks = 0; ks < 4; ++ks) {
    int a_off = sw_idx(sub * 16 + m16, ks * 32 + quad * 8);
    half8 ah = *(const half8*)(Ah_ + a_off);
    half8 al = *(const half8*)(Al_ + a_off);
#pragma unroll
    for (int c2 = 0; c2 < 2; ++c2) {
      int ct = ww * 2 + c2;
      int boff = ((ct * 4 + ks) * 64 + lane) * 8;
      mfma3(acc[c2], ah, al, *(const half8*)(Wh + boff), *(const half8*)(Wl + boff));
    }
  }
#pragma unroll
  for (int c2 = 0; c2 < 2; ++c2) {
#pragma unroll
    for (int reg = 0; reg < 4; ++reg) {
      int rl = sub * 16 + quad * 4 + reg;
      int col = ww * 32 + c2 * 16 + m16;
      float x = fmaxf(acc[c2][reg], 0.f);
      _Float16 hi = (_Float16)x;
      int a = sw_idx(rl, col);
      Dh[a] = hi;
      Dl[a] = (_Float16)(x - (float)hi);
    }
  }
  __syncthreads();
}

// full 3-layer MLP from LDS input S0/S1; scratch S2/S3; final -> global
__device__ __forceinline__ void mlp_from_lds(
    _Float16* S0, _Float16* S1, _Float16* S2, _Float16* S3, int M, int rb,
    const _Float16* __restrict__ W1h, const _Float16* __restrict__ W1l, const float* __restrict__ b1,
    const _Float16* __restrict__ W2h, const _Float16* __restrict__ W2l, const float* __restrict__ b2,
    const _Float16* __restrict__ W3h, const _Float16* __restrict__ W3l, const float* __restrict__ b3,
    float* __restrict__ out) {
  int tid = threadIdx.x;
  mlp_layer(S0, S1, W1h, W1l, b1, S2, S3, tid);
  mlp_layer(S2, S3, W2h, W2l, b2, S0, S1, tid);
  int lane = tid & 63, w = tid >> 6, sub = w >> 2, ww = w & 3;
  int m16 = lane & 15, quad = lane >> 4;
  f32x4 acc[2];
#pragma unroll
  for (int c2 = 0; c2 < 2; ++c2) {
    float bv = b3[ww * 32 + c2 * 16 + m16];
    acc[c2] = (f32x4){bv, bv, bv, bv};
  }
#pragma unroll
  for (int ks = 0; ks < 4; ++ks) {
    int a_off = sw_idx(sub * 16 + m16, ks * 32 + quad * 8);
    half8 ah = *(const half8*)(S0 + a_off);
    half8 al = *(const half8*)(S1 + a_off);
#pragma unroll
    for (int c2 = 0; c2 < 2; ++c2) {
      int ct = ww * 2 + c2;
      int boff = ((ct * 4 + ks) * 64 + lane) * 8;
      mfma3(acc[c2], ah, al, *(const half8*)(W3h + boff), *(const half8*)(W3l + boff));
    }
  }
#pragma unroll
  for (int c2 = 0; c2 < 2; ++c2) {
#pragma unroll
    for (int reg = 0; reg < 4; ++reg) {
      int row = rb + sub * 16 + quad * 4 + reg;
      int col = ww * 32 + c2 * 16 + m16;
      if (row < M) out[(size_t)row * DIM + col] = acc[c2][reg];
    }
  }
}

// ---------------- standalone MLP (initial phase A): global h -> va ----------------
__global__ __launch_bounds__(512, 2) void mlp3_mfma(
    const float* __restrict__ X, int M,
    const _Float16* __restrict__ W1h, const _Float16* __restrict__ W1l, const float* __restrict__ b1,
    const _Float16* __restrict__ W2h, const _Float16* __restrict__ W2l, const float* __restrict__ b2,
    const _Float16* __restrict__ W3h, const _Float16* __restrict__ W3l, const float* __restrict__ b3,
    float* __restrict__ out) {
  __shared__ _Float16 S0[4096], S1[4096], S2[4096], S3[4096];
  int tid = threadIdx.x;
  int rb = blockIdx.x << 5;
  stage_rows(X, M, rb, S0, S1, tid);
  __syncthreads();
  mlp_from_lds(S0, S1, S2, S3, M, rb, W1h, W1l, b1, W2h, W2l, b2, W3h, W3l, b3, out);
}

// ---------------- fused LSTM (+ optional row-local MLP) ----------------
// 512 threads, 32 rows/block; wave w: sub=w>>2 (row half), ww=w&3 (col group of 32)
template <bool DO_MLP>
__global__ __launch_bounds__(512, 2) void lstm_fused(
    const int* __restrict__ ptr, const int* __restrict__ nzidx, const float* __restrict__ va_in,
    float* __restrict__ hbuf, float* __restrict__ cbuf, int M,
    const _Float16* __restrict__ Wxh, const _Float16* __restrict__ Wxl,
    const _Float16* __restrict__ Whh_, const _Float16* __restrict__ Whl,
    const float* __restrict__ bih, const float* __restrict__ bhh,
    const _Float16* __restrict__ W1h, const _Float16* __restrict__ W1l, const float* __restrict__ b1,
    const _Float16* __restrict__ W2h, const _Float16* __restrict__ W2l, const float* __restrict__ b2,
    const _Float16* __restrict__ W3h, const _Float16* __restrict__ W3l, const float* __restrict__ b3,
    float* __restrict__ va_out) {
  __shared__ _Float16 Xh[4096], Xl[4096], Hh[4096], Hl[4096];
  int tid = threadIdx.x;
  int rb = blockIdx.x << 5;
  stage_rows(hbuf, M, rb, Hh, Hl, tid);
  gather_rows(ptr, nzidx, va_in, M, rb, Xh, Xl, tid);
  __syncthreads();

  int lane = tid & 63, w = tid >> 6, sub = w >> 2, ww = w & 3;
  int m16 = lane & 15, quad = lane >> 4;
  f32x4 acc[4][2];
#pragma unroll
  for (int g = 0; g < 4; ++g)
#pragma unroll
    for (int c2 = 0; c2 < 2; ++c2) {
      int col = g * 128 + ww * 32 + c2 * 16 + m16;
      float bv = bih[col] + bhh[col];
      acc[g][c2] = (f32x4){bv, bv, bv, bv};
    }
  // X @ Wih^T
#pragma unroll
  for (int ks = 0; ks < 4; ++ks) {
    int a_off = sw_idx(sub * 16 + m16, ks * 32 + quad * 8);
    half8 ah = *(const half8*)(Xh + a_off);
    half8 al = *(const half8*)(Xl + a_off);
#pragma unroll
    for (int g = 0; g < 4; ++g)
#pragma unroll
      for (int c2 = 0; c2 < 2; ++c2) {
        int ct = g * 8 + ww * 2 + c2;
        int boff = ((ct * 4 + ks) * 64 + lane) * 8;
        mfma3(acc[g][c2], ah, al, *(const half8*)(Wxh + boff), *(const half8*)(Wxl + boff));
      }
  }
  // H @ Whh^T
#pragma unroll
  for (int ks = 0; ks < 4; ++ks) {
    int a_off = sw_idx(sub * 16 + m16, ks * 32 + quad * 8);
    half8 ah = *(const half8*)(Hh + a_off);
    half8 al = *(const half8*)(Hl + a_off);
#pragma unroll
    for (int g = 0; g < 4; ++g)
#pragma unroll
      for (int c2 = 0; c2 < 2; ++c2) {
        int ct = g * 8 + ww * 2 + c2;
        int boff = ((ct * 4 + ks) * 64 + lane) * 8;
        mfma3(acc[g][c2], ah, al, *(const half8*)(Whh_ + boff), *(const half8*)(Whl + boff));
      }
  }

  if (DO_MLP) __syncthreads();  // all waves done reading Xh/Xl/Hh/Hl before overwrite

  // elementwise epilogue (gate order i,f,g,o); h,c -> global; h_new -> LDS (A-layout)
#pragma unroll
  for (int c2 = 0; c2 < 2; ++c2)
#pragma unroll
    for (int reg = 0; reg < 4; ++reg) {
      int rl = sub * 16 + quad * 4 + reg;
      int row = rb + rl;
      int col = ww * 32 + c2 * 16 + m16;
      float hn = 0.f;
      if (row < M) {
        float iv = sigf(acc[0][c2][reg]);
        float fv = sigf(acc[1][c2][reg]);
        float gv = tanh_fast(acc[2][c2][reg]);
        float ov = sigf(acc[3][c2][reg]);
        size_t o = (size_t)row * DIM + col;
        float cn = fv * cbuf[o] + iv * gv;
        cbuf[o] = cn;
        hn = ov * tanh_fast(cn);
        hbuf[o] = hn;
      }
      if (DO_MLP) {
        int a = sw_idx(rl, col);
        _Float16 hi = (_Float16)hn;
        Xh[a] = hi;
        Xl[a] = (_Float16)(hn - (float)hi);
      }
    }
  if (DO_MLP) {
    __syncthreads();
    mlp_from_lds(Xh, Xl, Hh, Hl, M, rb, W1h, W1l, b1, W2h, W2l, b2, W3h, W3l, b3, va_out);
  }
}

// ---------------- final vote MLP (fp32, runs once) ----------------
__device__ __forceinline__ void tile_gemm(const float* S, const float* __restrict__ W,
                                          int colB, int rowB, float acc[4][4]) {
#pragma unroll 4
  for (int kc = 0; kc < DIM; kc += 4) {
    float4 xv[4], wv[4];
#pragma unroll
    for (int r = 0; r < 4; ++r) xv[r] = *(const float4*)(S + (rowB + r) * DIM + kc);
#pragma unroll
    for (int c = 0; c < 4; ++c) wv[c] = *(const float4*)(W + (size_t)(colB + c) * DIM + kc);
#pragma unroll
    for (int r = 0; r < 4; ++r)
#pragma unroll
      for (int c = 0; c < 4; ++c)
        acc[r][c] += xv[r].x * wv[c].x + xv[r].y * wv[c].y + xv[r].z * wv[c].z + xv[r].w * wv[c].w;
  }
}

__device__ __forceinline__ void layer_lds(const float* Sin, float* Sout,
                                          const float* __restrict__ W, const float* __restrict__ B,
                                          bool relu, int colB, int rowB) {
  float acc[4][4];
#pragma unroll
  for (int r = 0; r < 4; ++r)
#pragma unroll
    for (int cc = 0; cc < 4; ++cc) acc[r][cc] = B[colB + cc];
  tile_gemm(Sin, W, colB, rowB, acc);
#pragma unroll
  for (int r = 0; r < 4; ++r) {
    float4 v;
    v.x = acc[r][0]; v.y = acc[r][1]; v.z = acc[r][2]; v.w = acc[r][3];
    if (relu) { v.x = fmaxf(v.x, 0.f); v.y = fmaxf(v.y, 0.f); v.z = fmaxf(v.z, 0.f); v.w = fmaxf(v.w, 0.f); }
    *(float4*)&Sout[(rowB + r) * DIM + colB] = v;
  }
  __syncthreads();
}

__global__ __launch_bounds__(256) void vote_kernel(
    const float* __restrict__ X, int M,
    const float* __restrict__ W1, const float* __restrict__ b1,
    const float* __restrict__ W2, const float* __restrict__ b2,
    const float* __restrict__ W3, const float* __restrict__ b3,
    float* __restrict__ out) {
  __shared__ float Xs[32 * DIM];
  __shared__ float Ys[32 * DIM];
  int tid = threadIdx.x;
  int rb = blockIdx.x * 32;
  int mrows = M - rb; if (mrows > 32) mrows = 32;
  {
    const float4* src = (const float4*)(X + (size_t)rb * DIM);
    float4* dst = (float4*)Xs;
    int nf4 = mrows * (DIM / 4);
    for (int t = tid; t < 32 * (DIM / 4); t += 256) {
      float4 v;
      if (t < nf4) v = src[t];
      else { v.x = v.y = v.z = v.w = 0.f; }
      dst[t] = v;
    }
  }
  __syncthreads();
  int tx = tid & 31, ty = tid >> 5;
  int colB = tx * 4, rowB = ty * 4;
  layer_lds(Xs, Ys, W1, b1, true, colB, rowB);
  layer_lds(Ys, Xs, W2, b2, true, colB, rowB);
  if (tid < 32) {
    int gr = rb + tid;
    if (gr < M) {
      float s = b3[0];
      for (int k = 0; k < DIM; ++k) s += Xs[tid * DIM + k] * W3[k];
      out[gr] = s;
    }
  }
}

#define SZ128 (DIM * DIM)
#define SZ512 (4 * DIM * DIM)
#define O_CM1 0
#define O_CM2 (SZ128)
#define O_CM3 (2 * SZ128)
#define O_PM1 (3 * SZ128)
#define O_PM2 (4 * SZ128)
#define O_PM3 (5 * SZ128)
#define O_VUX ((size_t)6 * SZ128)
#define O_VUH ((size_t)6 * SZ128 + SZ512)
#define O_NUX ((size_t)6 * SZ128 + 2 * SZ512)
#define O_NUH ((size_t)6 * SZ128 + 3 * SZ512)

extern "C" void kernel_launch(void* const* d_in, const int* in_sizes, int n_in,
                              void* d_out, int out_size, void* d_ws, size_t ws_size,
                              hipStream_t stream) {
  const float* adj    = (const float*)d_in[0];
  const int*   values = (const int*)d_in[1];
  const int N       = in_sizes[1];                  // 9000
  const int n_nodes = in_sizes[0] / N;              // 8000
  const int n_vars  = N - n_nodes;                  // 1000

  const float* true_W  = (const float*)d_in[3];
  const float* true_b  = (const float*)d_in[4];
  const float* false_W = (const float*)d_in[5];
  const float* false_b = (const float*)d_in[6];
  const float* cm_W1 = (const float*)d_in[7];
  const float* cm_b1 = (const float*)d_in[8];
  const float* cm_W2 = (const float*)d_in[9];
  const float* cm_b2 = (const float*)d_in[10];
  const float* cm_W3 = (const float*)d_in[11];
  const float* cm_b3 = (const float*)d_in[12];
  const float* pm_W1 = (const float*)d_in[13];
  const float* pm_b1 = (const float*)d_in[14];
  const float* pm_W2 = (const float*)d_in[15];
  const float* pm_b2 = (const float*)d_in[16];
  const float* pm_W3 = (const float*)d_in[17];
  const float* pm_b3 = (const float*)d_in[18];
  const float* vv_W1 = (const float*)d_in[19];
  const float* vv_b1 = (const float*)d_in[20];
  const float* vv_W2 = (const float*)d_in[21];
  const float* vv_b2 = (const float*)d_in[22];
  const float* vv_W3 = (const float*)d_in[23];
  const float* vv_b3 = (const float*)d_in[24];
  const float* vu_Wih = (const float*)d_in[25];
  const float* vu_Whh = (const float*)d_in[26];
  const float* vu_bih = (const float*)d_in[27];
  const float* vu_bhh = (const float*)d_in[28];
  const float* nu_Wih = (const float*)d_in[29];
  const float* nu_Whh = (const float*)d_in[30];
  const float* nu_bih = (const float*)d_in[31];
  const float* nu_bhh = (const float*)d_in[32];

  uintptr_t p = (uintptr_t)d_ws;
  auto take = [&](size_t bytes) -> void* {
    uintptr_t cur = (p + 255) & ~(uintptr_t)255;
    p = cur + bytes;
    return (void*)cur;
  };
  float* h   = (float*)take((size_t)N * DIM * sizeof(float));
  float* cb  = (float*)take((size_t)N * DIM * sizeof(float));
  float* va1 = (float*)take((size_t)N * DIM * sizeof(float));
  float* va2 = (float*)take((size_t)N * DIM * sizeof(float));
  int* row_ptr = (int*)take((size_t)(n_nodes + 1) * sizeof(int));
  int* col_ptr = (int*)take((size_t)(N + 1) * sizeof(int));
  int* cnts    = (int*)take((size_t)(n_nodes + N) * sizeof(int));
  int* row_cnt = cnts;
  int* col_cnt = cnts + n_nodes;
  int* col_idx = (int*)take((size_t)NNZ_CAP * sizeof(int));
  int* row_idx = (int*)take((size_t)NNZ_CAP * sizeof(int));

  size_t tot_pack = (size_t)6 * SZ128 + (size_t)4 * SZ512;
  _Float16* packh = (_Float16*)take(tot_pack * sizeof(_Float16));
  _Float16* packl = (_Float16*)take(tot_pack * sizeof(_Float16));

  hipMemsetAsync(cnts, 0, (size_t)(n_nodes + N) * sizeof(int), stream);
  dim3 cgrid(n_nodes, (N + 255) / 256);
  count_nz_kernel<<<cgrid, 256, 0, stream>>>(adj, row_cnt, col_cnt, N);
  scan_kernel<<<1, 256, 0, stream>>>(row_cnt, row_ptr, n_nodes);
  scan_kernel<<<1, 256, 0, stream>>>(col_cnt, col_ptr, N);
  fill_csr_kernel<<<n_nodes, 64, 0, stream>>>(adj, row_ptr, col_idx, N);
  fill_csc_kernel<<<(N + 63) / 64, 64, 0, stream>>>(adj, col_ptr, row_idx, n_nodes, N);
  init_hc_kernel<<<(N * DIM + 255) / 256, 256, 0, stream>>>(values, true_W, true_b,
                                                            false_W, false_b, h, cb, N);

  auto pack = [&](const float* src, int out_dim, size_t o) {
    pack_w_kernel<<<(out_dim * DIM + 255) / 256, 256, 0, stream>>>(src, out_dim,
                                                                   packh + o, packl + o);
  };
  pack(cm_W1, DIM, O_CM1); pack(cm_W2, DIM, O_CM2); pack(cm_W3, DIM, O_CM3);
  pack(pm_W1, DIM, O_PM1); pack(pm_W2, DIM, O_PM2); pack(pm_W3, DIM, O_PM3);
  pack(vu_Wih, 4 * DIM, O_VUX); pack(vu_Whh, 4 * DIM, O_VUH);
  pack(nu_Wih, 4 * DIM, O_NUX); pack(nu_Whh, 4 * DIM, O_NUH);

  int tiles_N = (N + 31) / 32, tiles_n = (n_nodes + 31) / 32;

  // A0: var_pre = cm_mlp(h) -> va1
  mlp3_mfma<<<tiles_N, 512, 0, stream>>>(h, N,
      packh + O_CM1, packl + O_CM1, cm_b1,
      packh + O_CM2, packl + O_CM2, cm_b2,
      packh + O_CM3, packl + O_CM3, cm_b3, va1);

  for (int r = 0; r < NROUNDS; ++r) {
    // B+C: vu-LSTM(csr-gather va1) on rows<n_nodes, then pm-MLP(h_new) -> va2
    lstm_fused<true><<<tiles_n, 512, 0, stream>>>(row_ptr, col_idx, va1, h, cb, n_nodes,
        packh + O_VUX, packl + O_VUX, packh + O_VUH, packl + O_VUH, vu_bih, vu_bhh,
        packh + O_PM1, packl + O_PM1, pm_b1,
        packh + O_PM2, packl + O_PM2, pm_b2,
        packh + O_PM3, packl + O_PM3, pm_b3, va2);
    if (r + 1 < NROUNDS) {
      // D+A(next): nu-LSTM(csc-gather va2) on all N rows, then cm-MLP(h_new) -> va1
      lstm_fused<true><<<tiles_N, 512, 0, stream>>>(col_ptr, row_idx, va2, h, cb, N,
          packh + O_NUX, packl + O_NUX, packh + O_NUH, packl + O_NUH, nu_bih, nu_bhh,
          packh + O_CM1, packl + O_CM1, cm_b1,
          packh + O_CM2, packl + O_CM2, cm_b2,
          packh + O_CM3, packl + O_CM3, cm_b3, va1);
    } else {
      // final D: nu-LSTM only
      lstm_fused<false><<<tiles_N, 512, 0, stream>>>(col_ptr, row_idx, va2, h, cb, N,
          packh + O_NUX, packl + O_NUX, packh + O_NUH, packl + O_NUH, nu_bih, nu_bhh,
          packh + O_CM1, packl + O_CM1, cm_b1,
          packh + O_CM2, packl + O_CM2, cm_b2,
          packh + O_CM3, packl + O_CM3, cm_b3, va1);
    }
  }

  vote_kernel<<<(n_vars + 31) / 32, 256, 0, stream>>>(h + (size_t)n_nodes * DIM, n_vars,
      vv_W1, vv_b1, vv_W2, vv_b2, vv_W3, vv_b3, (float*)d_out);
}

// Round 8
// 10860.313 us; speedup vs baseline: 6.2635x; 1.2321x over previous
//
#include <hip/hip_runtime.h>
#include <cstddef>
#include <cstdint>

#define DIM 128
#define NROUNDS 120
#define NNZ_CAP (1 << 20)

typedef _Float16 half8 __attribute__((ext_vector_type(8)));
typedef float f32x4 __attribute__((ext_vector_type(4)));
typedef unsigned long long u64;

__device__ __forceinline__ float sigf(float x) { return 1.f / (1.f + __expf(-x)); }
__device__ __forceinline__ float tanh_fast(float x) { return 2.f / (1.f + __expf(-2.f * x)) - 1.f; }

// ---------------- sparse build (deterministic) ----------------
__global__ void count_nz_kernel(const float* __restrict__ adj, int* __restrict__ row_cnt,
                                int* __restrict__ col_cnt, int ncols) {
  int i = blockIdx.x;
  int j = blockIdx.y * blockDim.x + threadIdx.x;
  bool nz = (j < ncols) && (adj[(size_t)i * ncols + j] != 0.f);
  unsigned long long m = __ballot(nz);
  if ((threadIdx.x & 63) == 0) {
    int c = __popcll(m);
    if (c) atomicAdd(&row_cnt[i], c);
  }
  if (nz) atomicAdd(&col_cnt[j], 1);
}

__global__ void scan_kernel(const int* __restrict__ cnt, int* __restrict__ ptr, int n) {
  __shared__ int sdata[256];
  int t = threadIdx.x;
  int per = (n + 255) / 256;
  int beg = t * per;
  int end = beg + per; if (end > n) end = n;
  int local = 0;
  for (int i = beg; i < end; ++i) local += cnt[i];
  sdata[t] = local;
  __syncthreads();
  for (int off = 1; off < 256; off <<= 1) {
    int v = (t >= off) ? sdata[t - off] : 0;
    __syncthreads();
    sdata[t] += v;
    __syncthreads();
  }
  int run = sdata[t] - local;
  for (int i = beg; i < end; ++i) { ptr[i] = run; run += cnt[i]; }
  if (t == 255) ptr[n] = sdata[255];
}

__global__ __launch_bounds__(64) void fill_csr_kernel(const float* __restrict__ adj,
                                                      const int* __restrict__ row_ptr,
                                                      int* __restrict__ col_idx, int ncols) {
  int row = blockIdx.x;
  int lane = threadIdx.x;
  int base = row_ptr[row];
  int cursor = 0;
  const float* arow = adj + (size_t)row * ncols;
  for (int j0 = 0; j0 < ncols; j0 += 64) {
    int j = j0 + lane;
    bool nz = (j < ncols) && (arow[j] != 0.f);
    u64 m = __ballot(nz);
    int pre = __popcll(m & ((1ull << lane) - 1));
    if (nz) col_idx[base + cursor + pre] = j;
    cursor += __popcll(m);
  }
}

__global__ __launch_bounds__(64) void fill_csc_kernel(const float* __restrict__ adj,
                                                      const int* __restrict__ col_ptr,
                                                      int* __restrict__ row_idx,
                                                      int nrows, int ncols) {
  int c = blockIdx.x * 64 + threadIdx.x;
  if (c >= ncols) return;
  int cur = col_ptr[c];
  for (int i = 0; i < nrows; ++i) {
    if (adj[(size_t)i * ncols + c] != 0.f) row_idx[cur++] = i;
  }
}

// ---------------- weight packing: MFMA 16x16x32 B-fragment order (split f16) ----------------
// B[k][n] = W[n][k]; lane L holds n = L&15, k = ks*32 + (L>>4)*8 + j (j=0..7)
// dst = ((nt*4 + ks)*64 + L)*8 + j, nt = n>>4
__global__ void pack_w_kernel(const float* __restrict__ src, int out_dim,
                              _Float16* __restrict__ dh, _Float16* __restrict__ dl) {
  int idx = blockIdx.x * 256 + threadIdx.x;
  if (idx >= out_dim * DIM) return;
  int n = idx >> 7, k = idx & 127;
  float x = src[idx];
  _Float16 hi = (_Float16)x;
  _Float16 lo = (_Float16)(x - (float)hi);
  int nt = n >> 4, ks = k >> 5;
  int L = ((k >> 3) & 3) * 16 + (n & 15);
  int j = k & 7;
  int dst = ((nt * 4 + ks) * 64 + L) * 8 + j;
  dh[dst] = hi; dl[dst] = lo;
}

// ---------------- init ----------------
__global__ void init_hc_kernel(const int* __restrict__ values, const float* __restrict__ tW,
                               const float* __restrict__ tb, const float* __restrict__ fW,
                               const float* __restrict__ fb, float* __restrict__ h,
                               float* __restrict__ c, int N) {
  int idx = blockIdx.x * blockDim.x + threadIdx.x;
  if (idx >= N * DIM) return;
  int row = idx >> 7, col = idx & (DIM - 1);
  float tv = tW[col] + tb[col];
  float fv = fW[col] + fb[col];
  h[idx] = (values[row] == 1) ? tv : fv;
  c[idx] = 0.f;
}

// ---------------- LDS swizzle (32 rows x 128, 8-chunk XOR) ----------------
__device__ __forceinline__ int sw_idx(int m, int k) {
  return (m << 7) + (((((k >> 3) ^ (m & 15))) << 3) | (k & 7));
}

// stage 32 fp32 rows -> split f16 LDS (512 threads: r=tid>>4, 8 floats each)
__device__ __forceinline__ void stage_rows(const float* __restrict__ src, int M, int rb,
                                           _Float16* Sh, _Float16* Sl, int tid) {
  int r = tid >> 4, q = tid & 15;
  int row = rb + r;
  float4 v0, v1;
  if (row < M) {
    const float4* s = (const float4*)(src + (size_t)row * DIM + q * 8);
    v0 = s[0]; v1 = s[1];
  } else {
    v0.x = v0.y = v0.z = v0.w = 0.f; v1 = v0;
  }
  int a = sw_idx(r, q * 8);
  float vv[8] = {v0.x, v0.y, v0.z, v0.w, v1.x, v1.y, v1.z, v1.w};
#pragma unroll
  for (int e = 0; e < 8; ++e) {
    _Float16 hi = (_Float16)vv[e];
    Sh[a + e] = hi;
    Sl[a + e] = (_Float16)(vv[e] - (float)hi);
  }
}

// deterministic binary-SpMM gather of 32 rows (f16 va) -> split f16 LDS (512 threads)
__device__ __forceinline__ void gather_rows(const int* __restrict__ ptr,
                                            const int* __restrict__ nzidx,
                                            const _Float16* __restrict__ va, int M, int rb,
                                            _Float16* Xh, _Float16* Xl, int tid) {
  int r = tid >> 4, seg = tid & 15;
  int row = rb + r;
  float a[8];
#pragma unroll
  for (int e = 0; e < 8; ++e) a[e] = 0.f;
  if (row < M) {
    int s = ptr[row], e_ = ptr[row + 1];
    int p = s;
    for (; p + 4 <= e_; p += 4) {
      int i0 = nzidx[p], i1 = nzidx[p + 1], i2 = nzidx[p + 2], i3 = nzidx[p + 3];
      half8 v0 = *(const half8*)(va + (size_t)i0 * DIM + seg * 8);
      half8 v1 = *(const half8*)(va + (size_t)i1 * DIM + seg * 8);
      half8 v2 = *(const half8*)(va + (size_t)i2 * DIM + seg * 8);
      half8 v3 = *(const half8*)(va + (size_t)i3 * DIM + seg * 8);
#pragma unroll
      for (int e = 0; e < 8; ++e)
        a[e] += ((float)v0[e] + (float)v1[e]) + ((float)v2[e] + (float)v3[e]);
    }
    for (; p < e_; ++p) {
      half8 v = *(const half8*)(va + (size_t)nzidx[p] * DIM + seg * 8);
#pragma unroll
      for (int e = 0; e < 8; ++e) a[e] += (float)v[e];
    }
  }
  int aoff = sw_idx(r, seg * 8);
#pragma unroll
  for (int e = 0; e < 8; ++e) {
    _Float16 hi = (_Float16)a[e];
    Xh[aoff + e] = hi;
    Xl[aoff + e] = (_Float16)(a[e] - (float)hi);
  }
}

__device__ __forceinline__ void mfma3(f32x4& acc, half8 ah, half8 al, half8 bh, half8 bl) {
  acc = __builtin_amdgcn_mfma_f32_16x16x32_f16(ah, bh, acc, 0, 0, 0);
  acc = __builtin_amdgcn_mfma_f32_16x16x32_f16(ah, bl, acc, 0, 0, 0);
  acc = __builtin_amdgcn_mfma_f32_16x16x32_f16(al, bh, acc, 0, 0, 0);
}

// one MLP layer with B-reuse: wave w owns col tile ct=w, BOTH row-subs share each B fragment
__device__ __forceinline__ void mlp_layer(const _Float16* Ah_, const _Float16* Al_,
                                          const _Float16* __restrict__ Wh,
                                          const _Float16* __restrict__ Wl,
                                          const float* __restrict__ B,
                                          _Float16* Dh, _Float16* Dl, int tid) {
  int lane = tid & 63, w = tid >> 6;
  int m16 = lane & 15, quad = lane >> 4;
  float bv = B[w * 16 + m16];
  f32x4 acc[2];
  acc[0] = (f32x4){bv, bv, bv, bv};
  acc[1] = acc[0];
#pragma unroll
  for (int ks = 0; ks < 4; ++ks) {
    int boff = ((w * 4 + ks) * 64 + lane) * 8;
    half8 bh = *(const half8*)(Wh + boff);
    half8 bl = *(const half8*)(Wl + boff);
#pragma unroll
    for (int sub = 0; sub < 2; ++sub) {
      int a_off = sw_idx(sub * 16 + m16, ks * 32 + quad * 8);
      mfma3(acc[sub], *(const half8*)(Ah_ + a_off), *(const half8*)(Al_ + a_off), bh, bl);
    }
  }
#pragma unroll
  for (int sub = 0; sub < 2; ++sub)
#pragma unroll
    for (int reg = 0; reg < 4; ++reg) {
      int rl = sub * 16 + quad * 4 + reg;
      int col = w * 16 + m16;
      float x = fmaxf(acc[sub][reg], 0.f);
      _Float16 hi = (_Float16)x;
      int a = sw_idx(rl, col);
      Dh[a] = hi;
      Dl[a] = (_Float16)(x - (float)hi);
    }
  __syncthreads();
}

// full 3-layer MLP from LDS input S0/S1; scratch S2/S3; final -> f16 global
__device__ __forceinline__ void mlp_from_lds(
    _Float16* S0, _Float16* S1, _Float16* S2, _Float16* S3, int M, int rb,
    const _Float16* __restrict__ W1h, const _Float16* __restrict__ W1l, const float* __restrict__ b1,
    const _Float16* __restrict__ W2h, const _Float16* __restrict__ W2l, const float* __restrict__ b2,
    const _Float16* __restrict__ W3h, const _Float16* __restrict__ W3l, const float* __restrict__ b3,
    _Float16* __restrict__ out) {
  int tid = threadIdx.x;
  mlp_layer(S0, S1, W1h, W1l, b1, S2, S3, tid);
  mlp_layer(S2, S3, W2h, W2l, b2, S0, S1, tid);
  int lane = tid & 63, w = tid >> 6;
  int m16 = lane & 15, quad = lane >> 4;
  float bv = b3[w * 16 + m16];
  f32x4 acc[2];
  acc[0] = (f32x4){bv, bv, bv, bv};
  acc[1] = acc[0];
#pragma unroll
  for (int ks = 0; ks < 4; ++ks) {
    int boff = ((w * 4 + ks) * 64 + lane) * 8;
    half8 bh = *(const half8*)(W3h + boff);
    half8 bl = *(const half8*)(W3l + boff);
#pragma unroll
    for (int sub = 0; sub < 2; ++sub) {
      int a_off = sw_idx(sub * 16 + m16, ks * 32 + quad * 8);
      mfma3(acc[sub], *(const half8*)(S0 + a_off), *(const half8*)(S1 + a_off), bh, bl);
    }
  }
#pragma unroll
  for (int sub = 0; sub < 2; ++sub)
#pragma unroll
    for (int reg = 0; reg < 4; ++reg) {
      int row = rb + sub * 16 + quad * 4 + reg;
      int col = w * 16 + m16;
      if (row < M) out[(size_t)row * DIM + col] = (_Float16)acc[sub][reg];
    }
}

// ---------------- standalone MLP (initial phase A): global h -> f16 va ----------------
__global__ __launch_bounds__(512, 2) void mlp3_mfma(
    const float* __restrict__ X, int M,
    const _Float16* __restrict__ W1h, const _Float16* __restrict__ W1l, const float* __restrict__ b1,
    const _Float16* __restrict__ W2h, const _Float16* __restrict__ W2l, const float* __restrict__ b2,
    const _Float16* __restrict__ W3h, const _Float16* __restrict__ W3l, const float* __restrict__ b3,
    _Float16* __restrict__ out) {
  __shared__ _Float16 S0[4096], S1[4096], S2[4096], S3[4096];
  int tid = threadIdx.x;
  int rb = blockIdx.x << 5;
  stage_rows(X, M, rb, S0, S1, tid);
  __syncthreads();
  mlp_from_lds(S0, S1, S2, S3, M, rb, W1h, W1l, b1, W2h, W2l, b2, W3h, W3l, b3, out);
}

// ---------------- fused LSTM (+ optional row-local MLP) ----------------
// 512 threads, 32 rows/block; wave w owns cols [w*16,w*16+16) of each gate, both row-subs
template <bool DO_MLP>
__global__ __launch_bounds__(512, 2) void lstm_fused(
    const int* __restrict__ ptr, const int* __restrict__ nzidx, const _Float16* __restrict__ va_in,
    float* __restrict__ hbuf, float* __restrict__ cbuf, int M,
    const _Float16* __restrict__ Wxh, const _Float16* __restrict__ Wxl,
    const _Float16* __restrict__ Whh_, const _Float16* __restrict__ Whl,
    const float* __restrict__ bih, const float* __restrict__ bhh,
    const _Float16* __restrict__ W1h, const _Float16* __restrict__ W1l, const float* __restrict__ b1,
    const _Float16* __restrict__ W2h, const _Float16* __restrict__ W2l, const float* __restrict__ b2,
    const _Float16* __restrict__ W3h, const _Float16* __restrict__ W3l, const float* __restrict__ b3,
    _Float16* __restrict__ va_out) {
  __shared__ _Float16 Xh[4096], Xl[4096], Hh[4096], Hl[4096];
  int tid = threadIdx.x;
  int rb = blockIdx.x << 5;
  stage_rows(hbuf, M, rb, Hh, Hl, tid);
  gather_rows(ptr, nzidx, va_in, M, rb, Xh, Xl, tid);
  __syncthreads();

  int lane = tid & 63, w = tid >> 6;
  int m16 = lane & 15, quad = lane >> 4;
  f32x4 acc[2][4];
#pragma unroll
  for (int g = 0; g < 4; ++g) {
    int col = g * 128 + w * 16 + m16;
    float bv = bih[col] + bhh[col];
    acc[0][g] = (f32x4){bv, bv, bv, bv};
    acc[1][g] = acc[0][g];
  }
  // H @ Whh^T (B-fragment loaded once, applied to both row-subs)
#pragma unroll
  for (int ks = 0; ks < 4; ++ks) {
#pragma unroll
    for (int g = 0; g < 4; ++g) {
      int ct = g * 8 + w;
      int boff = ((ct * 4 + ks) * 64 + lane) * 8;
      half8 bh = *(const half8*)(Whh_ + boff);
      half8 bl = *(const half8*)(Whl + boff);
#pragma unroll
      for (int sub = 0; sub < 2; ++sub) {
        int a_off = sw_idx(sub * 16 + m16, ks * 32 + quad * 8);
        mfma3(acc[sub][g], *(const half8*)(Hh + a_off), *(const half8*)(Hl + a_off), bh, bl);
      }
    }
  }
  // X @ Wih^T
#pragma unroll
  for (int ks = 0; ks < 4; ++ks) {
#pragma unroll
    for (int g = 0; g < 4; ++g) {
      int ct = g * 8 + w;
      int boff = ((ct * 4 + ks) * 64 + lane) * 8;
      half8 bh = *(const half8*)(Wxh + boff);
      half8 bl = *(const half8*)(Wxl + boff);
#pragma unroll
      for (int sub = 0; sub < 2; ++sub) {
        int a_off = sw_idx(sub * 16 + m16, ks * 32 + quad * 8);
        mfma3(acc[sub][g], *(const half8*)(Xh + a_off), *(const half8*)(Xl + a_off), bh, bl);
      }
    }
  }

  if (DO_MLP) __syncthreads();  // all waves done reading Xh/Xl/Hh/Hl before overwrite

  // elementwise epilogue (gate order i,f,g,o); h,c -> global; h_new -> LDS (A-layout)
#pragma unroll
  for (int sub = 0; sub < 2; ++sub)
#pragma unroll
    for (int reg = 0; reg < 4; ++reg) {
      int rl = sub * 16 + quad * 4 + reg;
      int row = rb + rl;
      int col = w * 16 + m16;
      float hn = 0.f;
      if (row < M) {
        float iv = sigf(acc[sub][0][reg]);
        float fv = sigf(acc[sub][1][reg]);
        float gv = tanh_fast(acc[sub][2][reg]);
        float ov = sigf(acc[sub][3][reg]);
        size_t o = (size_t)row * DIM + col;
        float cn = fv * cbuf[o] + iv * gv;
        cbuf[o] = cn;
        hn = ov * tanh_fast(cn);
        hbuf[o] = hn;
      }
      if (DO_MLP) {
        int a = sw_idx(rl, col);
        _Float16 hi = (_Float16)hn;
        Xh[a] = hi;
        Xl[a] = (_Float16)(hn - (float)hi);
      }
    }
  if (DO_MLP) {
    __syncthreads();
    mlp_from_lds(Xh, Xl, Hh, Hl, M, rb, W1h, W1l, b1, W2h, W2l, b2, W3h, W3l, b3, va_out);
  }
}

// ---------------- final vote MLP (fp32, runs once) ----------------
__device__ __forceinline__ void tile_gemm(const float* S, const float* __restrict__ W,
                                          int colB, int rowB, float acc[4][4]) {
#pragma unroll 4
  for (int kc = 0; kc < DIM; kc += 4) {
    float4 xv[4], wv[4];
#pragma unroll
    for (int r = 0; r < 4; ++r) xv[r] = *(const float4*)(S + (rowB + r) * DIM + kc);
#pragma unroll
    for (int c = 0; c < 4; ++c) wv[c] = *(const float4*)(W + (size_t)(colB + c) * DIM + kc);
#pragma unroll
    for (int r = 0; r < 4; ++r)
#pragma unroll
      for (int c = 0; c < 4; ++c)
        acc[r][c] += xv[r].x * wv[c].x + xv[r].y * wv[c].y + xv[r].z * wv[c].z + xv[r].w * wv[c].w;
  }
}

__device__ __forceinline__ void layer_lds(const float* Sin, float* Sout,
                                          const float* __restrict__ W, const float* __restrict__ B,
                                          bool relu, int colB, int rowB) {
  float acc[4][4];
#pragma unroll
  for (int r = 0; r < 4; ++r)
#pragma unroll
    for (int cc = 0; cc < 4; ++cc) acc[r][cc] = B[colB + cc];
  tile_gemm(Sin, W, colB, rowB, acc);
#pragma unroll
  for (int r = 0; r < 4; ++r) {
    float4 v;
    v.x = acc[r][0]; v.y = acc[r][1]; v.z = acc[r][2]; v.w = acc[r][3];
    if (relu) { v.x = fmaxf(v.x, 0.f); v.y = fmaxf(v.y, 0.f); v.z = fmaxf(v.z, 0.f); v.w = fmaxf(v.w, 0.f); }
    *(float4*)&Sout[(rowB + r) * DIM + colB] = v;
  }
  __syncthreads();
}

__global__ __launch_bounds__(256) void vote_kernel(
    const float* __restrict__ X, int M,
    const float* __restrict__ W1, const float* __restrict__ b1,
    const float* __restrict__ W2, const float* __restrict__ b2,
    const float* __restrict__ W3, const float* __restrict__ b3,
    float* __restrict__ out) {
  __shared__ float Xs[32 * DIM];
  __shared__ float Ys[32 * DIM];
  int tid = threadIdx.x;
  int rb = blockIdx.x * 32;
  int mrows = M - rb; if (mrows > 32) mrows = 32;
  {
    const float4* src = (const float4*)(X + (size_t)rb * DIM);
    float4* dst = (float4*)Xs;
    int nf4 = mrows * (DIM / 4);
    for (int t = tid; t < 32 * (DIM / 4); t += 256) {
      float4 v;
      if (t < nf4) v = src[t];
      else { v.x = v.y = v.z = v.w = 0.f; }
      dst[t] = v;
    }
  }
  __syncthreads();
  int tx = tid & 31, ty = tid >> 5;
  int colB = tx * 4, rowB = ty * 4;
  layer_lds(Xs, Ys, W1, b1, true, colB, rowB);
  layer_lds(Ys, Xs, W2, b2, true, colB, rowB);
  if (tid < 32) {
    int gr = rb + tid;
    if (gr < M) {
      float s = b3[0];
      for (int k = 0; k < DIM; ++k) s += Xs[tid * DIM + k] * W3[k];
      out[gr] = s;
    }
  }
}

#define SZ128 (DIM * DIM)
#define SZ512 (4 * DIM * DIM)
#define O_CM1 0
#define O_CM2 (SZ128)
#define O_CM3 (2 * SZ128)
#define O_PM1 (3 * SZ128)
#define O_PM2 (4 * SZ128)
#define O_PM3 (5 * SZ128)
#define O_VUX ((size_t)6 * SZ128)
#define O_VUH ((size_t)6 * SZ128 + SZ512)
#define O_NUX ((size_t)6 * SZ128 + 2 * SZ512)
#define O_NUH ((size_t)6 * SZ128 + 3 * SZ512)

extern "C" void kernel_launch(void* const* d_in, const int* in_sizes, int n_in,
                              void* d_out, int out_size, void* d_ws, size_t ws_size,
                              hipStream_t stream) {
  const float* adj    = (const float*)d_in[0];
  const int*   values = (const int*)d_in[1];
  const int N       = in_sizes[1];                  // 9000
  const int n_nodes = in_sizes[0] / N;              // 8000
  const int n_vars  = N - n_nodes;                  // 1000

  const float* true_W  = (const float*)d_in[3];
  const float* true_b  = (const float*)d_in[4];
  const float* false_W = (const float*)d_in[5];
  const float* false_b = (const float*)d_in[6];
  const float* cm_W1 = (const float*)d_in[7];
  const float* cm_b1 = (const float*)d_in[8];
  const float* cm_W2 = (const float*)d_in[9];
  const float* cm_b2 = (const float*)d_in[10];
  const float* cm_W3 = (const float*)d_in[11];
  const float* cm_b3 = (const float*)d_in[12];
  const float* pm_W1 = (const float*)d_in[13];
  const float* pm_b1 = (const float*)d_in[14];
  const float* pm_W2 = (const float*)d_in[15];
  const float* pm_b2 = (const float*)d_in[16];
  const float* pm_W3 = (const float*)d_in[17];
  const float* pm_b3 = (const float*)d_in[18];
  const float* vv_W1 = (const float*)d_in[19];
  const float* vv_b1 = (const float*)d_in[20];
  const float* vv_W2 = (const float*)d_in[21];
  const float* vv_b2 = (const float*)d_in[22];
  const float* vv_W3 = (const float*)d_in[23];
  const float* vv_b3 = (const float*)d_in[24];
  const float* vu_Wih = (const float*)d_in[25];
  const float* vu_Whh = (const float*)d_in[26];
  const float* vu_bih = (const float*)d_in[27];
  const float* vu_bhh = (const float*)d_in[28];
  const float* nu_Wih = (const float*)d_in[29];
  const float* nu_Whh = (const float*)d_in[30];
  const float* nu_bih = (const float*)d_in[31];
  const float* nu_bhh = (const float*)d_in[32];

  uintptr_t p = (uintptr_t)d_ws;
  auto take = [&](size_t bytes) -> void* {
    uintptr_t cur = (p + 255) & ~(uintptr_t)255;
    p = cur + bytes;
    return (void*)cur;
  };
  float* h   = (float*)take((size_t)N * DIM * sizeof(float));
  float* cb  = (float*)take((size_t)N * DIM * sizeof(float));
  _Float16* va1 = (_Float16*)take((size_t)N * DIM * sizeof(_Float16));
  _Float16* va2 = (_Float16*)take((size_t)N * DIM * sizeof(_Float16));
  int* row_ptr = (int*)take((size_t)(n_nodes + 1) * sizeof(int));
  int* col_ptr = (int*)take((size_t)(N + 1) * sizeof(int));
  int* cnts    = (int*)take((size_t)(n_nodes + N) * sizeof(int));
  int* row_cnt = cnts;
  int* col_cnt = cnts + n_nodes;
  int* col_idx = (int*)take((size_t)NNZ_CAP * sizeof(int));
  int* row_idx = (int*)take((size_t)NNZ_CAP * sizeof(int));

  size_t tot_pack = (size_t)6 * SZ128 + (size_t)4 * SZ512;
  _Float16* packh = (_Float16*)take(tot_pack * sizeof(_Float16));
  _Float16* packl = (_Float16*)take(tot_pack * sizeof(_Float16));

  hipMemsetAsync(cnts, 0, (size_t)(n_nodes + N) * sizeof(int), stream);
  dim3 cgrid(n_nodes, (N + 255) / 256);
  count_nz_kernel<<<cgrid, 256, 0, stream>>>(adj, row_cnt, col_cnt, N);
  scan_kernel<<<1, 256, 0, stream>>>(row_cnt, row_ptr, n_nodes);
  scan_kernel<<<1, 256, 0, stream>>>(col_cnt, col_ptr, N);
  fill_csr_kernel<<<n_nodes, 64, 0, stream>>>(adj, row_ptr, col_idx, N);
  fill_csc_kernel<<<(N + 63) / 64, 64, 0, stream>>>(adj, col_ptr, row_idx, n_nodes, N);
  init_hc_kernel<<<(N * DIM + 255) / 256, 256, 0, stream>>>(values, true_W, true_b,
                                                            false_W, false_b, h, cb, N);

  auto pack = [&](const float* src, int out_dim, size_t o) {
    pack_w_kernel<<<(out_dim * DIM + 255) / 256, 256, 0, stream>>>(src, out_dim,
                                                                   packh + o, packl + o);
  };
  pack(cm_W1, DIM, O_CM1); pack(cm_W2, DIM, O_CM2); pack(cm_W3, DIM, O_CM3);
  pack(pm_W1, DIM, O_PM1); pack(pm_W2, DIM, O_PM2); pack(pm_W3, DIM, O_PM3);
  pack(vu_Wih, 4 * DIM, O_VUX); pack(vu_Whh, 4 * DIM, O_VUH);
  pack(nu_Wih, 4 * DIM, O_NUX); pack(nu_Whh, 4 * DIM, O_NUH);

  int tiles_N = (N + 31) / 32, tiles_n = (n_nodes + 31) / 32;

  // A0: var_pre = cm_mlp(h) -> va1 (f16)
  mlp3_mfma<<<tiles_N, 512, 0, stream>>>(h, N,
      packh + O_CM1, packl + O_CM1, cm_b1,
      packh + O_CM2, packl + O_CM2, cm_b2,
      packh + O_CM3, packl + O_CM3, cm_b3, va1);

  for (int r = 0; r < NROUNDS; ++r) {
    // B+C: vu-LSTM(csr-gather va1) on rows<n_nodes, then pm-MLP(h_new) -> va2
    lstm_fused<true><<<tiles_n, 512, 0, stream>>>(row_ptr, col_idx, va1, h, cb, n_nodes,
        packh + O_VUX, packl + O_VUX, packh + O_VUH, packl + O_VUH, vu_bih, vu_bhh,
        packh + O_PM1, packl + O_PM1, pm_b1,
        packh + O_PM2, packl + O_PM2, pm_b2,
        packh + O_PM3, packl + O_PM3, pm_b3, va2);
    if (r + 1 < NROUNDS) {
      // D+A(next): nu-LSTM(csc-gather va2) on all N rows, then cm-MLP(h_new) -> va1
      lstm_fused<true><<<tiles_N, 512, 0, stream>>>(col_ptr, row_idx, va2, h, cb, N,
          packh + O_NUX, packl + O_NUX, packh + O_NUH, packl + O_NUH, nu_bih, nu_bhh,
          packh + O_CM1, packl + O_CM1, cm_b1,
          packh + O_CM2, packl + O_CM2, cm_b2,
          packh + O_CM3, packl + O_CM3, cm_b3, va1);
    } else {
      // final D: nu-LSTM only
      lstm_fused<false><<<tiles_N, 512, 0, stream>>>(col_ptr, row_idx, va2, h, cb, N,
          packh + O_NUX, packl + O_NUX, packh + O_NUH, packl + O_NUH, nu_bih, nu_bhh,
          packh + O_CM1, packl + O_CM1, cm_b1,
          packh + O_CM2, packl + O_CM2, cm_b2,
          packh + O_CM3, packl + O_CM3, cm_b3, va1);
    }
  }

  vote_kernel<<<(n_vars + 31) / 32, 256, 0, stream>>>(h + (size_t)n_nodes * DIM, n_vars,
      vv_W1, vv_b1, vv_W2, vv_b2, vv_W3, vv_b3, (float*)d_out);
}